// Round 17
// baseline (127.802 us; speedup 1.0000x reference)
//
#include <hip/hip_runtime.h>
#include <stdint.h>

// ---------------------------------------------------------------------------
// B=32, C=4, S=256, L=256, Din=Dout=256
// Pipeline (4 dispatches):
//   K0 corr_table:  blocks 0..127: corr[b] = fm[b]@fm[b]^T (4-term bf16 MFMA)
//                   blocks 128..640: dphi table (131073 nodes) + counter zero
//   K1 decide_fast: one block = one adj row; lerp+gumbel32, dynamic guard
//                   thr = 4e-4 + slope*6e-4; adj bf16; fused rowsum
//   K2 decide_exact: ONE WAVE PER ITEM exact f64 (dot from fm + lane-parallel
//                   mlp64 + gumbel64); patches adj + rowsumF
//   K3 fused_out:   per (z, 32-row group): phase1 X=rs*(adj@F[z]) in regs,
//                   X->LDS bf16 hi/lo, phase2 out = X@Wl + bl. X never in HBM.
//   ROUND-14 BUG FIXED: B staging now maps lanes with nq=(tid&31)*4 over two
//   128-row halves (lane write stride 320B = 16 dw mod 32 -> 2-way, free).
//   Round-14's nq*8 on 80B pitch put all 32 lanes in bank 0 (66M conflicts).
// threefry partitionable (jax key 42): bits(i) = o0^o1 of tf2x32((0,42),(0,i))
// ---------------------------------------------------------------------------

#define TBL_INTERVALS 131072
#define TBL_MIN -128.0f
#define TBL_SCALE 512.0f
#define WL_CAP 131072u
#define FUSED_LDS 74752  // union(Aadj[32][264], Xh/Xl[32][264]x2)=33792 + Bh/Bl[256][40]x2=40960

typedef __attribute__((ext_vector_type(8))) short short8v;
typedef __attribute__((ext_vector_type(4))) short short4v;
typedef __attribute__((ext_vector_type(4))) float float4v;

__device__ __forceinline__ void threefry2x32(uint32_t x0, uint32_t x1,
                                             uint32_t& o0, uint32_t& o1) {
  const uint32_t ks0 = 0u;
  const uint32_t ks1 = 42u;
  const uint32_t ks2 = 0x1BD11BDAu ^ ks0 ^ ks1;
  const uint32_t ks[3] = {ks0, ks1, ks2};
  const uint32_t rot[2][4] = {{13u, 15u, 26u, 6u}, {17u, 29u, 16u, 24u}};
  x0 += ks0;
  x1 += ks1;
#pragma unroll
  for (int i = 0; i < 5; ++i) {
#pragma unroll
    for (int j = 0; j < 4; ++j) {
      const uint32_t r = rot[i & 1][j];
      x0 += x1;
      x1 = (x1 << r) | (x1 >> (32u - r));
      x1 ^= x0;
    }
    x0 += ks[(i + 1) % 3];
    x1 += ks[(i + 2) % 3] + (uint32_t)(i + 1);
  }
  o0 = x0;
  o1 = x1;
}

__device__ __forceinline__ float uniform_at(uint32_t j) {
  uint32_t o0, o1;
  threefry2x32(0u, j, o0, o1);
  const uint32_t bits = o0 ^ o1;
  uint32_t fb = (bits >> 9) | 0x3F800000u;
  float frac = __uint_as_float(fb) - 1.0f;
  return fmaxf(frac + 1e-10f, 1e-10f);
}

__device__ __forceinline__ double gumbel64_at(uint32_t j) {
  double t = -log((double)uniform_at(j));
  return -log(t);
}

__device__ __forceinline__ float gumbel32_at(uint32_t j) {
  float t = -logf(uniform_at(j));
  return -logf(t);
}

__device__ __forceinline__ double gelu_d(double x) {
  return 0.5 * x * (1.0 + erf(x * 0.70710678118654752440));
}

__device__ __forceinline__ float gelu_f(float x) {
  return 0.5f * x * (1.0f + erff(x * 0.70710678f));
}

__device__ __forceinline__ float mlp32(float corr, const float* __restrict__ W1,
                                       const float* __restrict__ b1,
                                       const float* __restrict__ W2,
                                       const float* __restrict__ b2,
                                       const float* __restrict__ W3,
                                       const float* __restrict__ b3) {
  float h1[16];
#pragma unroll
  for (int u = 0; u < 16; ++u) h1[u] = gelu_f(fmaf(corr, W1[u], b1[u]));
  float h2[8];
#pragma unroll
  for (int v = 0; v < 8; ++v) {
    float x = b2[v];
#pragma unroll
    for (int u = 0; u < 16; ++u) x = fmaf(h1[u], W2[u * 8 + v], x);
    h2[v] = gelu_f(x);
  }
  float l0 = b3[0], l1 = b3[1];
#pragma unroll
  for (int v = 0; v < 8; ++v) {
    l0 = fmaf(h2[v], W3[v * 2 + 0], l0);
    l1 = fmaf(h2[v], W3[v * 2 + 1], l1);
  }
  return l0 - l1;
}

// RNE f32 -> bf16 split
__device__ __forceinline__ void split_bf16(float x, short& h, short& l) {
  uint32_t u = __float_as_uint(x);
  uint32_t hr = (u + 0x7FFFu + ((u >> 16) & 1u)) >> 16;
  float hf = __uint_as_float(hr << 16);
  float lo = x - hf;
  uint32_t v = __float_as_uint(lo);
  uint32_t lr = (v + 0x7FFFu + ((v >> 16) & 1u)) >> 16;
  h = (short)hr;
  l = (short)lr;
}

// ---------------------------------------------------------------------------
// K0: corr tiles (blocks 0..127) + dphi table (blocks 128..640) + counter.
// ---------------------------------------------------------------------------
__global__ __launch_bounds__(256) void corr_table_kernel(
    const float* __restrict__ fm, float* __restrict__ corr,
    const float* __restrict__ W1, const float* __restrict__ b1,
    const float* __restrict__ W2, const float* __restrict__ b2,
    const float* __restrict__ W3, const float* __restrict__ b3,
    float* __restrict__ tbl, uint32_t* __restrict__ counter) {
  if (blockIdx.x >= 128) {
    const int i = (int)(blockIdx.x - 128) * 256 + threadIdx.x;
    if (blockIdx.x == 128 && threadIdx.x == 0) counter[0] = 0u;
    if (i <= TBL_INTERVALS) {
      const float x = TBL_MIN + (float)i * (1.0f / TBL_SCALE);
      tbl[i] = mlp32(x, W1, b1, W2, b2, W3, b3);
    }
    return;
  }

  const int bid = blockIdx.x;
  const int b = bid >> 2;
  const int row0 = ((bid >> 1) & 1) * 128;
  const int col0 = (bid & 1) * 128;
  const float* base = fm + (size_t)b * 65536;

  __shared__ short Ah[128][40];
  __shared__ short Al[128][40];
  __shared__ short Bh[128][40];  // [n][k]
  __shared__ short Bl[128][40];

  const int tid = threadIdx.x;
  const int w = tid >> 6;
  const int wr = (w >> 1) * 64;
  const int wc = (w & 1) * 64;
  const int lane = tid & 63;
  const int fcol = lane & 15;
  const int kg = lane >> 4;

  const int am = tid >> 1;
  const int ak = (tid & 1) * 16;

  float4v acc[4][4];
#pragma unroll
  for (int i = 0; i < 4; ++i)
#pragma unroll
    for (int j = 0; j < 4; ++j) acc[i][j] = (float4v)(0.0f);

  for (int k0 = 0; k0 < 256; k0 += 32) {
    float4 av[4], bv[4];
#pragma unroll
    for (int q = 0; q < 4; ++q) {
      av[q] = *(const float4*)(base + (size_t)(row0 + am) * 256 + k0 + ak + q * 4);
      bv[q] = *(const float4*)(base + (size_t)(col0 + am) * 256 + k0 + ak + q * 4);
    }

    __syncthreads();

    {
      short h[16], l[16];
#pragma unroll
      for (int q = 0; q < 4; ++q) {
        split_bf16(av[q].x, h[q * 4 + 0], l[q * 4 + 0]);
        split_bf16(av[q].y, h[q * 4 + 1], l[q * 4 + 1]);
        split_bf16(av[q].z, h[q * 4 + 2], l[q * 4 + 2]);
        split_bf16(av[q].w, h[q * 4 + 3], l[q * 4 + 3]);
      }
      *(short8v*)&Ah[am][ak] = *(short8v*)&h[0];
      *(short8v*)&Ah[am][ak + 8] = *(short8v*)&h[8];
      *(short8v*)&Al[am][ak] = *(short8v*)&l[0];
      *(short8v*)&Al[am][ak + 8] = *(short8v*)&l[8];
#pragma unroll
      for (int q = 0; q < 4; ++q) {
        split_bf16(bv[q].x, h[q * 4 + 0], l[q * 4 + 0]);
        split_bf16(bv[q].y, h[q * 4 + 1], l[q * 4 + 1]);
        split_bf16(bv[q].z, h[q * 4 + 2], l[q * 4 + 2]);
        split_bf16(bv[q].w, h[q * 4 + 3], l[q * 4 + 3]);
      }
      *(short8v*)&Bh[am][ak] = *(short8v*)&h[0];
      *(short8v*)&Bh[am][ak + 8] = *(short8v*)&h[8];
      *(short8v*)&Bl[am][ak] = *(short8v*)&l[0];
      *(short8v*)&Bl[am][ak + 8] = *(short8v*)&l[8];
    }
    __syncthreads();

    short8v afh[4], afl[4], bfh[4], bfl[4];
#pragma unroll
    for (int im = 0; im < 4; ++im) {
      afh[im] = *(const short8v*)&Ah[wr + im * 16 + fcol][kg * 8];
      afl[im] = *(const short8v*)&Al[wr + im * 16 + fcol][kg * 8];
    }
#pragma unroll
    for (int in = 0; in < 4; ++in) {
      bfh[in] = *(const short8v*)&Bh[wc + in * 16 + fcol][kg * 8];
      bfl[in] = *(const short8v*)&Bl[wc + in * 16 + fcol][kg * 8];
    }
#pragma unroll
    for (int im = 0; im < 4; ++im)
#pragma unroll
      for (int in = 0; in < 4; ++in) {
        acc[im][in] = __builtin_amdgcn_mfma_f32_16x16x32_bf16(
            afh[im], bfh[in], acc[im][in], 0, 0, 0);
        acc[im][in] = __builtin_amdgcn_mfma_f32_16x16x32_bf16(
            afh[im], bfl[in], acc[im][in], 0, 0, 0);
        acc[im][in] = __builtin_amdgcn_mfma_f32_16x16x32_bf16(
            afl[im], bfh[in], acc[im][in], 0, 0, 0);
        acc[im][in] = __builtin_amdgcn_mfma_f32_16x16x32_bf16(
            afl[im], bfl[in], acc[im][in], 0, 0, 0);
      }
  }

  float* Cb = corr + (size_t)b * 65536;
#pragma unroll
  for (int in = 0; in < 4; ++in) {
    const int col = col0 + wc + in * 16 + fcol;
#pragma unroll
    for (int im = 0; im < 4; ++im) {
      const int rbase = row0 + wr + im * 16 + kg * 4;
#pragma unroll
      for (int r = 0; r < 4; ++r)
        Cb[(size_t)(rbase + r) * 256 + col] = acc[im][in][r];
    }
  }
}

// ---------------------------------------------------------------------------
// K1: decide_fast + fused rowsum. One block = one (b,s) row. grid 8192 x 256.
// ---------------------------------------------------------------------------
__global__ __launch_bounds__(256) void decide_fast_kernel(
    const float* __restrict__ corr, const float* __restrict__ tbl,
    unsigned short* __restrict__ adj_bin, uint32_t* __restrict__ counter,
    uint32_t* __restrict__ worklist, float* __restrict__ rowsumF) {
  const uint32_t flat = blockIdx.x * 256u + threadIdx.x;  // < 2,097,152
  const int t = threadIdx.x;
  const int s = blockIdx.x & 255;

  float a = 1.0f;
  bool pend = false;
  if (t != s) {
    const float cf = corr[flat];
    if (fabsf(cf) >= 127.0f) {
      pend = true;
      a = 0.0f;
    } else {
      const float xf = (cf - TBL_MIN) * TBL_SCALE;
      const int i = (int)xf;
      const float fr = xf - (float)i;
      const float t0v = tbl[i];
      const float t1v = tbl[i + 1];
      const float dt = t1v - t0v;
      const float dphi = fmaf(fr, dt, t0v);

      const float g0 = gumbel32_at(2u * flat);
      const float g1 = gumbel32_at(2u * flat + 1u);
      const float d = dphi - (g1 - g0);
      const float thr = fmaf(fabsf(dt), 0.3072f, 4e-4f);
      if (fabsf(d) >= thr) {
        a = (d >= 0.0f) ? 1.0f : 0.0f;
      } else {
        pend = true;
        a = 0.0f;
      }
    }
  }
  if (pend) {
    const uint32_t idx = atomicAdd(counter, 1u);
    if (idx < WL_CAP) worklist[idx] = flat;
  }
  adj_bin[flat] = (a == 1.0f) ? (unsigned short)0x3F80u : (unsigned short)0u;

  float sum = a;
#pragma unroll
  for (int off = 32; off; off >>= 1) sum += __shfl_xor(sum, off);
  __shared__ float red[4];
  if ((threadIdx.x & 63) == 0) red[threadIdx.x >> 6] = sum;
  __syncthreads();
  if (threadIdx.x == 0)
    rowsumF[blockIdx.x] = red[0] + red[1] + red[2] + red[3];
}

// ---------------------------------------------------------------------------
// K2: exact f64 resolve, ONE WAVE PER ITEM (validated path). grid 2048 x 256.
// ---------------------------------------------------------------------------
__global__ __launch_bounds__(256) void decide_exact_kernel(
    const float* __restrict__ fm, const uint32_t* __restrict__ counter,
    const uint32_t* __restrict__ worklist,
    const float* __restrict__ W1, const float* __restrict__ b1,
    const float* __restrict__ W2, const float* __restrict__ b2,
    const float* __restrict__ W3, const float* __restrict__ b3,
    unsigned short* __restrict__ adj_bin, float* __restrict__ rowsumF) {
  const uint32_t n = min(counter[0], WL_CAP);
  const uint32_t waveId = (blockIdx.x * 256u + threadIdx.x) >> 6;
  const uint32_t nWaves = (gridDim.x * 256u) >> 6;
  const int lane = threadIdx.x & 63;

  for (uint32_t it = waveId; it < n; it += nWaves) {
    const uint32_t flat = worklist[it];
    const uint32_t bb = flat >> 16;
    const uint32_t ss = (flat >> 8) & 255u;
    const uint32_t tt = flat & 255u;

    const float* S = fm + ((size_t)bb * 256 + ss) * 256;
    const float* T = fm + ((size_t)bb * 256 + tt) * 256;
    double p = 0.0;
#pragma unroll
    for (int q = 0; q < 4; ++q) {
      const int k = lane + q * 64;
      p += (double)S[k] * (double)T[k];
    }
#pragma unroll
    for (int off = 32; off; off >>= 1) p += __shfl_xor(p, off);
    const double acc = p;

    const double ga = gumbel64_at(2u * flat + (uint32_t)(lane & 1));

    const int u = lane & 15;
    const double h1 = gelu_d(acc * (double)W1[u] + (double)b1[u]);

    const int v = lane & 7;
    double sv = (double)b2[v];
#pragma unroll
    for (int uu = 0; uu < 16; ++uu) {
      const double h1u = __shfl(h1, uu);
      sv += h1u * (double)W2[uu * 8 + v];
    }
    const double h2 = gelu_d(sv);

    double l0 = (double)b3[0], l1 = (double)b3[1];
#pragma unroll
    for (int vv = 0; vv < 8; ++vv) {
      const double h2v = __shfl(h2, vv);
      l0 += h2v * (double)W3[vv * 2 + 0];
      l1 += h2v * (double)W3[vv * 2 + 1];
    }

    const double G0 = __shfl(ga, 0);
    const double G1 = __shfl(ga, 1);
    if (lane == 0) {
      const bool one = (l0 + G0 >= l1 + G1);
      adj_bin[flat] = one ? (unsigned short)0x3F80u : (unsigned short)0u;
      if (one) atomicAdd(&rowsumF[flat >> 8], 1.0f);
    }
  }
}

// ---------------------------------------------------------------------------
// K3: fused output. Block = (z = bid&127, rowgroup rg = bid>>7 of 32 S-rows).
// Phase 1: X(32x256) = rs * (adj_rows @ F[z]) in regs (binA x 2-term B).
// Transition: X -> LDS as bf16 hi/lo (over Aadj region).
// Phase 2: out = X @ Wl + bl (3-term), A-frags from LDS.
// LDS: union(Aadj[32][264], Xh/Xl[32][264]) @0 (33792B), Bh/Bl[256][40] @33792.
// B staging: nq=(tid&31)*4, two 128-row halves (fixed round-14 conflict).
// ---------------------------------------------------------------------------
__global__ __launch_bounds__(256) void fused_out_kernel(
    const unsigned short* __restrict__ adjp, const float* __restrict__ F,
    const float* __restrict__ Wl, const float* __restrict__ bl,
    const float* __restrict__ rowsumF, float* __restrict__ out) {
  extern __shared__ char smem[];
  short* Aadj = (short*)smem;               // [32][264] (phase 1)
  short* Xh = (short*)smem;                 // [32][264] (phase 2)
  short* Xl = Xh + 32 * 264;
  short* Bh = (short*)(smem + 33792);       // [256][40] (n-major, k minor)
  short* Bl = Bh + 256 * 40;

  const int bid = blockIdx.x;
  const int z = bid & 127;   // batch b*4+c; same-z blocks share bid%8 -> XCD
  const int rg = bid >> 7;   // 0..7
  const int b = z >> 2;
  const int row0 = rg * 32;

  const unsigned short* Ab = adjp + (size_t)b * 65536 + (size_t)row0 * 256;
  const float* Fb = F + (size_t)z * 65536;
  const float* rsb = rowsumF + b * 256 + row0;
  float* Ob = out + (size_t)z * 65536 + (size_t)row0 * 256;

  const int tid = threadIdx.x;
  const int w = tid >> 6;
  const int wc2 = w * 64;  // wave's 64 output cols
  const int lane = tid & 63;
  const int fcol = lane & 15;
  const int kg = lane >> 4;

  const int nq = (tid & 31) * 4;  // B staging: 4 cols per half (FIXED)
  const int kb = (tid >> 5) * 4;  // B staging: 4 ks

  // stage adj rows (32x256 bf16, raw copy - binary values exact)
  {
    const int r = tid >> 3;
    const int c0 = (tid & 7) * 32;
#pragma unroll
    for (int q = 0; q < 4; ++q) {
      short8v v = *(const short8v*)(Ab + (size_t)r * 256 + c0 + q * 8);
      *(short8v*)&Aadj[r * 264 + c0 + q * 8] = v;
    }
  }

  float4v acc[2][4];
#pragma unroll
  for (int i = 0; i < 2; ++i)
#pragma unroll
    for (int j = 0; j < 4; ++j) acc[i][j] = (float4v)(0.0f);

  // ---- phase 1: acc = adj @ F ----
  for (int k0 = 0; k0 < 256; k0 += 32) {
    float4 bv[4][2];
#pragma unroll
    for (int j = 0; j < 4; ++j) {
      bv[j][0] = *(const float4*)(Fb + (size_t)(k0 + kb + j) * 256 + nq);
      bv[j][1] = *(const float4*)(Fb + (size_t)(k0 + kb + j) * 256 + 128 + nq);
    }
    __syncthreads();  // fences Aadj staging (k0=0) and prior frag reads
#pragma unroll
    for (int half = 0; half < 2; ++half) {
#pragma unroll
      for (int i = 0; i < 4; ++i) {
        short h[4], l[4];
#pragma unroll
        for (int j = 0; j < 4; ++j) {
          const float4& f = bv[j][half];
          const float x = (i == 0) ? f.x : (i == 1) ? f.y : (i == 2) ? f.z : f.w;
          split_bf16(x, h[j], l[j]);
        }
        const int rowb = half * 128 + nq + i;
        *(short4v*)&Bh[rowb * 40 + kb] = *(short4v*)&h[0];
        *(short4v*)&Bl[rowb * 40 + kb] = *(short4v*)&l[0];
      }
    }
    __syncthreads();

    short8v af[2], bfh[4], bfl[4];
#pragma unroll
    for (int im = 0; im < 2; ++im)
      af[im] = *(const short8v*)&Aadj[(im * 16 + fcol) * 264 + k0 + kg * 8];
#pragma unroll
    for (int in = 0; in < 4; ++in) {
      bfh[in] = *(const short8v*)&Bh[(wc2 + in * 16 + fcol) * 40 + kg * 8];
      bfl[in] = *(const short8v*)&Bl[(wc2 + in * 16 + fcol) * 40 + kg * 8];
    }
#pragma unroll
    for (int im = 0; im < 2; ++im)
#pragma unroll
      for (int in = 0; in < 4; ++in) {
        acc[im][in] = __builtin_amdgcn_mfma_f32_16x16x32_bf16(
            af[im], bfh[in], acc[im][in], 0, 0, 0);
        acc[im][in] = __builtin_amdgcn_mfma_f32_16x16x32_bf16(
            af[im], bfl[in], acc[im][in], 0, 0, 0);
      }
  }

  // ---- transition: X = rs*acc -> LDS bf16 hi/lo (over Aadj) ----
  __syncthreads();  // all phase-1 LDS reads complete
  {
    float rsv[2][4];
#pragma unroll
    for (int im = 0; im < 2; ++im)
#pragma unroll
      for (int r = 0; r < 4; ++r)
        rsv[im][r] = 1.0f / rsb[im * 16 + kg * 4 + r];
#pragma unroll
    for (int im = 0; im < 2; ++im)
#pragma unroll
      for (int in = 0; in < 4; ++in) {
        const int col = wc2 + in * 16 + fcol;
#pragma unroll
        for (int r = 0; r < 4; ++r) {
          const int row = im * 16 + kg * 4 + r;
          short h, l;
          split_bf16(acc[im][in][r] * rsv[im][r], h, l);
          Xh[row * 264 + col] = h;
          Xl[row * 264 + col] = l;
        }
      }
  }
#pragma unroll
  for (int i = 0; i < 2; ++i)
#pragma unroll
    for (int j = 0; j < 4; ++j) acc[i][j] = (float4v)(0.0f);

  // ---- phase 2: out = X @ Wl + bl (3-term) ----
  for (int k0 = 0; k0 < 256; k0 += 32) {
    float4 bv[4][2];
#pragma unroll
    for (int j = 0; j < 4; ++j) {
      bv[j][0] = *(const float4*)(Wl + (size_t)(k0 + kb + j) * 256 + nq);
      bv[j][1] = *(const float4*)(Wl + (size_t)(k0 + kb + j) * 256 + 128 + nq);
    }
    __syncthreads();  // fences X writes (k0=0) and prior frag reads
#pragma unroll
    for (int half = 0; half < 2; ++half) {
#pragma unroll
      for (int i = 0; i < 4; ++i) {
        short h[4], l[4];
#pragma unroll
        for (int j = 0; j < 4; ++j) {
          const float4& f = bv[j][half];
          const float x = (i == 0) ? f.x : (i == 1) ? f.y : (i == 2) ? f.z : f.w;
          split_bf16(x, h[j], l[j]);
        }
        const int rowb = half * 128 + nq + i;
        *(short4v*)&Bh[rowb * 40 + kb] = *(short4v*)&h[0];
        *(short4v*)&Bl[rowb * 40 + kb] = *(short4v*)&l[0];
      }
    }
    __syncthreads();

    short8v afh[2], afl[2], bfh[4], bfl[4];
#pragma unroll
    for (int im = 0; im < 2; ++im) {
      afh[im] = *(const short8v*)&Xh[(im * 16 + fcol) * 264 + k0 + kg * 8];
      afl[im] = *(const short8v*)&Xl[(im * 16 + fcol) * 264 + k0 + kg * 8];
    }
#pragma unroll
    for (int in = 0; in < 4; ++in) {
      bfh[in] = *(const short8v*)&Bh[(wc2 + in * 16 + fcol) * 40 + kg * 8];
      bfl[in] = *(const short8v*)&Bl[(wc2 + in * 16 + fcol) * 40 + kg * 8];
    }
#pragma unroll
    for (int im = 0; im < 2; ++im)
#pragma unroll
      for (int in = 0; in < 4; ++in) {
        acc[im][in] = __builtin_amdgcn_mfma_f32_16x16x32_bf16(
            afh[im], bfh[in], acc[im][in], 0, 0, 0);
        acc[im][in] = __builtin_amdgcn_mfma_f32_16x16x32_bf16(
            afh[im], bfl[in], acc[im][in], 0, 0, 0);
        acc[im][in] = __builtin_amdgcn_mfma_f32_16x16x32_bf16(
            afl[im], bfh[in], acc[im][in], 0, 0, 0);
      }
  }

  // ---- epilogue ----
#pragma unroll
  for (int in = 0; in < 4; ++in) {
    const int col = wc2 + in * 16 + fcol;
    const float bvx = bl[col];
#pragma unroll
    for (int im = 0; im < 2; ++im) {
      const int rbase = im * 16 + kg * 4;
#pragma unroll
      for (int r = 0; r < 4; ++r)
        Ob[(size_t)(rbase + r) * 256 + col] = acc[im][in][r] + bvx;
    }
  }
}

extern "C" void kernel_launch(void* const* d_in, const int* in_sizes, int n_in,
                              void* d_out, int out_size, void* d_ws,
                              size_t ws_size, hipStream_t stream) {
  const float* features = (const float*)d_in[0];
  const float* fm       = (const float*)d_in[1];
  const float* W1 = (const float*)d_in[2];
  const float* b1 = (const float*)d_in[3];
  const float* W2 = (const float*)d_in[4];
  const float* b2 = (const float*)d_in[5];
  const float* W3 = (const float*)d_in[6];
  const float* b3 = (const float*)d_in[7];
  const float* Wl = (const float*)d_in[8];
  const float* bl = (const float*)d_in[9];
  float* out = (float*)d_out;

  // ws layout:
  //   tbl      @ 0       .. 524KB
  //   rowsumF  @ 576KB   .. 608KB   (8192 f32)
  //   counter  @ 640KB   (4B), worklist follows (512KB)
  //   adj_bin  @ 2.0MB   .. 6.2MB   (bf16 ushort)
  //   corr     @ 10.5MB  .. 18.9MB  (f32, dead after decide_fast)
  char* ws = (char*)d_ws;
  float* tbl          = (float*)ws;
  float* rowsumF      = (float*)(ws + 576u * 1024u);
  uint32_t* counter   = (uint32_t*)(ws + 640u * 1024u);
  uint32_t* worklist  = counter + 16;
  unsigned short* adj = (unsigned short*)(ws + 2u * 1024u * 1024u);
  float* corr         = (float*)(ws + 10800u * 1024u);

  // allow >64KB dynamic LDS for the fused kernel (deterministic, idempotent)
  hipFuncSetAttribute((const void*)fused_out_kernel,
                      hipFuncAttributeMaxDynamicSharedMemorySize, FUSED_LDS);

  corr_table_kernel<<<dim3(641), 256, 0, stream>>>(fm, corr, W1, b1, W2, b2,
                                                   W3, b3, tbl, counter);
  decide_fast_kernel<<<dim3(8192), 256, 0, stream>>>(corr, tbl, adj, counter,
                                                     worklist, rowsumF);
  decide_exact_kernel<<<dim3(2048), 256, 0, stream>>>(fm, counter, worklist,
                                                      W1, b1, W2, b2, W3, b3,
                                                      adj, rowsumF);
  fused_out_kernel<<<dim3(1024), 256, FUSED_LDS, stream>>>(adj, features, Wl,
                                                           bl, rowsumF, out);
}

// Round 18
// 103.486 us; speedup vs baseline: 1.2350x; 1.2350x over previous
//
#include <hip/hip_runtime.h>
#include <stdint.h>

// ---------------------------------------------------------------------------
// B=32, C=4, S=256, L=256, Din=Dout=256
// Pipeline (4 dispatches):
//   K0 corr_table:  blocks 0..127: corr[b] = fm[b]@fm[b]^T (4-term bf16 MFMA)
//                   blocks 128..640: dphi table (131073 nodes) + counter zero
//   K1 decide_fast: one block = one adj row; lerp+gumbel32, dynamic guard
//                   thr = 4e-4 + slope*6e-4; adj bf16; fused rowsum
//   K2 decide_exact: ONE WAVE PER ITEM exact f64 (dot from fm + lane-parallel
//                   mlp64 + gumbel64); patches adj + rowsumF
//   K3 fused_out:   per (z, 32-row group): phase1 X=rs*(adj@F[z]) in regs,
//                   X->LDS bf16 hi/lo, phase2 out = X@Wl + bl. X never in HBM.
//   ROUND-17 BUG FIXED: B staging lane->row stride was 4 rows (320B = 16 dw
//   mod 32 -> 32 lanes on 2 bank slots -> 16-way, 32.6M conflicts). Now
//   n = (tid&31) + 32*i (stride 1 row = 20 dw, gcd 4 -> 2 lanes/slot, ~free);
//   loads become 32 coalesced scalar dwords held in regs across the barrier.
// threefry partitionable (jax key 42): bits(i) = o0^o1 of tf2x32((0,42),(0,i))
// ---------------------------------------------------------------------------

#define TBL_INTERVALS 131072
#define TBL_MIN -128.0f
#define TBL_SCALE 512.0f
#define WL_CAP 131072u
#define FUSED_LDS 74752  // union(Aadj[32][264], Xh/Xl[32][264]x2)=33792 + Bh/Bl[256][40]x2=40960

typedef __attribute__((ext_vector_type(8))) short short8v;
typedef __attribute__((ext_vector_type(4))) short short4v;
typedef __attribute__((ext_vector_type(4))) float float4v;

__device__ __forceinline__ void threefry2x32(uint32_t x0, uint32_t x1,
                                             uint32_t& o0, uint32_t& o1) {
  const uint32_t ks0 = 0u;
  const uint32_t ks1 = 42u;
  const uint32_t ks2 = 0x1BD11BDAu ^ ks0 ^ ks1;
  const uint32_t ks[3] = {ks0, ks1, ks2};
  const uint32_t rot[2][4] = {{13u, 15u, 26u, 6u}, {17u, 29u, 16u, 24u}};
  x0 += ks0;
  x1 += ks1;
#pragma unroll
  for (int i = 0; i < 5; ++i) {
#pragma unroll
    for (int j = 0; j < 4; ++j) {
      const uint32_t r = rot[i & 1][j];
      x0 += x1;
      x1 = (x1 << r) | (x1 >> (32u - r));
      x1 ^= x0;
    }
    x0 += ks[(i + 1) % 3];
    x1 += ks[(i + 2) % 3] + (uint32_t)(i + 1);
  }
  o0 = x0;
  o1 = x1;
}

__device__ __forceinline__ float uniform_at(uint32_t j) {
  uint32_t o0, o1;
  threefry2x32(0u, j, o0, o1);
  const uint32_t bits = o0 ^ o1;
  uint32_t fb = (bits >> 9) | 0x3F800000u;
  float frac = __uint_as_float(fb) - 1.0f;
  return fmaxf(frac + 1e-10f, 1e-10f);
}

__device__ __forceinline__ double gumbel64_at(uint32_t j) {
  double t = -log((double)uniform_at(j));
  return -log(t);
}

__device__ __forceinline__ float gumbel32_at(uint32_t j) {
  float t = -logf(uniform_at(j));
  return -logf(t);
}

__device__ __forceinline__ double gelu_d(double x) {
  return 0.5 * x * (1.0 + erf(x * 0.70710678118654752440));
}

__device__ __forceinline__ float gelu_f(float x) {
  return 0.5f * x * (1.0f + erff(x * 0.70710678f));
}

__device__ __forceinline__ float mlp32(float corr, const float* __restrict__ W1,
                                       const float* __restrict__ b1,
                                       const float* __restrict__ W2,
                                       const float* __restrict__ b2,
                                       const float* __restrict__ W3,
                                       const float* __restrict__ b3) {
  float h1[16];
#pragma unroll
  for (int u = 0; u < 16; ++u) h1[u] = gelu_f(fmaf(corr, W1[u], b1[u]));
  float h2[8];
#pragma unroll
  for (int v = 0; v < 8; ++v) {
    float x = b2[v];
#pragma unroll
    for (int u = 0; u < 16; ++u) x = fmaf(h1[u], W2[u * 8 + v], x);
    h2[v] = gelu_f(x);
  }
  float l0 = b3[0], l1 = b3[1];
#pragma unroll
  for (int v = 0; v < 8; ++v) {
    l0 = fmaf(h2[v], W3[v * 2 + 0], l0);
    l1 = fmaf(h2[v], W3[v * 2 + 1], l1);
  }
  return l0 - l1;
}

// RNE f32 -> bf16 split
__device__ __forceinline__ void split_bf16(float x, short& h, short& l) {
  uint32_t u = __float_as_uint(x);
  uint32_t hr = (u + 0x7FFFu + ((u >> 16) & 1u)) >> 16;
  float hf = __uint_as_float(hr << 16);
  float lo = x - hf;
  uint32_t v = __float_as_uint(lo);
  uint32_t lr = (v + 0x7FFFu + ((v >> 16) & 1u)) >> 16;
  h = (short)hr;
  l = (short)lr;
}

// ---------------------------------------------------------------------------
// K0: corr tiles (blocks 0..127) + dphi table (blocks 128..640) + counter.
// ---------------------------------------------------------------------------
__global__ __launch_bounds__(256) void corr_table_kernel(
    const float* __restrict__ fm, float* __restrict__ corr,
    const float* __restrict__ W1, const float* __restrict__ b1,
    const float* __restrict__ W2, const float* __restrict__ b2,
    const float* __restrict__ W3, const float* __restrict__ b3,
    float* __restrict__ tbl, uint32_t* __restrict__ counter) {
  if (blockIdx.x >= 128) {
    const int i = (int)(blockIdx.x - 128) * 256 + threadIdx.x;
    if (blockIdx.x == 128 && threadIdx.x == 0) counter[0] = 0u;
    if (i <= TBL_INTERVALS) {
      const float x = TBL_MIN + (float)i * (1.0f / TBL_SCALE);
      tbl[i] = mlp32(x, W1, b1, W2, b2, W3, b3);
    }
    return;
  }

  const int bid = blockIdx.x;
  const int b = bid >> 2;
  const int row0 = ((bid >> 1) & 1) * 128;
  const int col0 = (bid & 1) * 128;
  const float* base = fm + (size_t)b * 65536;

  __shared__ short Ah[128][40];
  __shared__ short Al[128][40];
  __shared__ short Bh[128][40];  // [n][k]
  __shared__ short Bl[128][40];

  const int tid = threadIdx.x;
  const int w = tid >> 6;
  const int wr = (w >> 1) * 64;
  const int wc = (w & 1) * 64;
  const int lane = tid & 63;
  const int fcol = lane & 15;
  const int kg = lane >> 4;

  const int am = tid >> 1;
  const int ak = (tid & 1) * 16;

  float4v acc[4][4];
#pragma unroll
  for (int i = 0; i < 4; ++i)
#pragma unroll
    for (int j = 0; j < 4; ++j) acc[i][j] = (float4v)(0.0f);

  for (int k0 = 0; k0 < 256; k0 += 32) {
    float4 av[4], bv[4];
#pragma unroll
    for (int q = 0; q < 4; ++q) {
      av[q] = *(const float4*)(base + (size_t)(row0 + am) * 256 + k0 + ak + q * 4);
      bv[q] = *(const float4*)(base + (size_t)(col0 + am) * 256 + k0 + ak + q * 4);
    }

    __syncthreads();

    {
      short h[16], l[16];
#pragma unroll
      for (int q = 0; q < 4; ++q) {
        split_bf16(av[q].x, h[q * 4 + 0], l[q * 4 + 0]);
        split_bf16(av[q].y, h[q * 4 + 1], l[q * 4 + 1]);
        split_bf16(av[q].z, h[q * 4 + 2], l[q * 4 + 2]);
        split_bf16(av[q].w, h[q * 4 + 3], l[q * 4 + 3]);
      }
      *(short8v*)&Ah[am][ak] = *(short8v*)&h[0];
      *(short8v*)&Ah[am][ak + 8] = *(short8v*)&h[8];
      *(short8v*)&Al[am][ak] = *(short8v*)&l[0];
      *(short8v*)&Al[am][ak + 8] = *(short8v*)&l[8];
#pragma unroll
      for (int q = 0; q < 4; ++q) {
        split_bf16(bv[q].x, h[q * 4 + 0], l[q * 4 + 0]);
        split_bf16(bv[q].y, h[q * 4 + 1], l[q * 4 + 1]);
        split_bf16(bv[q].z, h[q * 4 + 2], l[q * 4 + 2]);
        split_bf16(bv[q].w, h[q * 4 + 3], l[q * 4 + 3]);
      }
      *(short8v*)&Bh[am][ak] = *(short8v*)&h[0];
      *(short8v*)&Bh[am][ak + 8] = *(short8v*)&h[8];
      *(short8v*)&Bl[am][ak] = *(short8v*)&l[0];
      *(short8v*)&Bl[am][ak + 8] = *(short8v*)&l[8];
    }
    __syncthreads();

    short8v afh[4], afl[4], bfh[4], bfl[4];
#pragma unroll
    for (int im = 0; im < 4; ++im) {
      afh[im] = *(const short8v*)&Ah[wr + im * 16 + fcol][kg * 8];
      afl[im] = *(const short8v*)&Al[wr + im * 16 + fcol][kg * 8];
    }
#pragma unroll
    for (int in = 0; in < 4; ++in) {
      bfh[in] = *(const short8v*)&Bh[wc + in * 16 + fcol][kg * 8];
      bfl[in] = *(const short8v*)&Bl[wc + in * 16 + fcol][kg * 8];
    }
#pragma unroll
    for (int im = 0; im < 4; ++im)
#pragma unroll
      for (int in = 0; in < 4; ++in) {
        acc[im][in] = __builtin_amdgcn_mfma_f32_16x16x32_bf16(
            afh[im], bfh[in], acc[im][in], 0, 0, 0);
        acc[im][in] = __builtin_amdgcn_mfma_f32_16x16x32_bf16(
            afh[im], bfl[in], acc[im][in], 0, 0, 0);
        acc[im][in] = __builtin_amdgcn_mfma_f32_16x16x32_bf16(
            afl[im], bfh[in], acc[im][in], 0, 0, 0);
        acc[im][in] = __builtin_amdgcn_mfma_f32_16x16x32_bf16(
            afl[im], bfl[in], acc[im][in], 0, 0, 0);
      }
  }

  float* Cb = corr + (size_t)b * 65536;
#pragma unroll
  for (int in = 0; in < 4; ++in) {
    const int col = col0 + wc + in * 16 + fcol;
#pragma unroll
    for (int im = 0; im < 4; ++im) {
      const int rbase = row0 + wr + im * 16 + kg * 4;
#pragma unroll
      for (int r = 0; r < 4; ++r)
        Cb[(size_t)(rbase + r) * 256 + col] = acc[im][in][r];
    }
  }
}

// ---------------------------------------------------------------------------
// K1: decide_fast + fused rowsum. One block = one (b,s) row. grid 8192 x 256.
// ---------------------------------------------------------------------------
__global__ __launch_bounds__(256) void decide_fast_kernel(
    const float* __restrict__ corr, const float* __restrict__ tbl,
    unsigned short* __restrict__ adj_bin, uint32_t* __restrict__ counter,
    uint32_t* __restrict__ worklist, float* __restrict__ rowsumF) {
  const uint32_t flat = blockIdx.x * 256u + threadIdx.x;  // < 2,097,152
  const int t = threadIdx.x;
  const int s = blockIdx.x & 255;

  float a = 1.0f;
  bool pend = false;
  if (t != s) {
    const float cf = corr[flat];
    if (fabsf(cf) >= 127.0f) {
      pend = true;
      a = 0.0f;
    } else {
      const float xf = (cf - TBL_MIN) * TBL_SCALE;
      const int i = (int)xf;
      const float fr = xf - (float)i;
      const float t0v = tbl[i];
      const float t1v = tbl[i + 1];
      const float dt = t1v - t0v;
      const float dphi = fmaf(fr, dt, t0v);

      const float g0 = gumbel32_at(2u * flat);
      const float g1 = gumbel32_at(2u * flat + 1u);
      const float d = dphi - (g1 - g0);
      const float thr = fmaf(fabsf(dt), 0.3072f, 4e-4f);
      if (fabsf(d) >= thr) {
        a = (d >= 0.0f) ? 1.0f : 0.0f;
      } else {
        pend = true;
        a = 0.0f;
      }
    }
  }
  if (pend) {
    const uint32_t idx = atomicAdd(counter, 1u);
    if (idx < WL_CAP) worklist[idx] = flat;
  }
  adj_bin[flat] = (a == 1.0f) ? (unsigned short)0x3F80u : (unsigned short)0u;

  float sum = a;
#pragma unroll
  for (int off = 32; off; off >>= 1) sum += __shfl_xor(sum, off);
  __shared__ float red[4];
  if ((threadIdx.x & 63) == 0) red[threadIdx.x >> 6] = sum;
  __syncthreads();
  if (threadIdx.x == 0)
    rowsumF[blockIdx.x] = red[0] + red[1] + red[2] + red[3];
}

// ---------------------------------------------------------------------------
// K2: exact f64 resolve, ONE WAVE PER ITEM (validated path). grid 2048 x 256.
// ---------------------------------------------------------------------------
__global__ __launch_bounds__(256) void decide_exact_kernel(
    const float* __restrict__ fm, const uint32_t* __restrict__ counter,
    const uint32_t* __restrict__ worklist,
    const float* __restrict__ W1, const float* __restrict__ b1,
    const float* __restrict__ W2, const float* __restrict__ b2,
    const float* __restrict__ W3, const float* __restrict__ b3,
    unsigned short* __restrict__ adj_bin, float* __restrict__ rowsumF) {
  const uint32_t n = min(counter[0], WL_CAP);
  const uint32_t waveId = (blockIdx.x * 256u + threadIdx.x) >> 6;
  const uint32_t nWaves = (gridDim.x * 256u) >> 6;
  const int lane = threadIdx.x & 63;

  for (uint32_t it = waveId; it < n; it += nWaves) {
    const uint32_t flat = worklist[it];
    const uint32_t bb = flat >> 16;
    const uint32_t ss = (flat >> 8) & 255u;
    const uint32_t tt = flat & 255u;

    const float* S = fm + ((size_t)bb * 256 + ss) * 256;
    const float* T = fm + ((size_t)bb * 256 + tt) * 256;
    double p = 0.0;
#pragma unroll
    for (int q = 0; q < 4; ++q) {
      const int k = lane + q * 64;
      p += (double)S[k] * (double)T[k];
    }
#pragma unroll
    for (int off = 32; off; off >>= 1) p += __shfl_xor(p, off);
    const double acc = p;

    const double ga = gumbel64_at(2u * flat + (uint32_t)(lane & 1));

    const int u = lane & 15;
    const double h1 = gelu_d(acc * (double)W1[u] + (double)b1[u]);

    const int v = lane & 7;
    double sv = (double)b2[v];
#pragma unroll
    for (int uu = 0; uu < 16; ++uu) {
      const double h1u = __shfl(h1, uu);
      sv += h1u * (double)W2[uu * 8 + v];
    }
    const double h2 = gelu_d(sv);

    double l0 = (double)b3[0], l1 = (double)b3[1];
#pragma unroll
    for (int vv = 0; vv < 8; ++vv) {
      const double h2v = __shfl(h2, vv);
      l0 += h2v * (double)W3[vv * 2 + 0];
      l1 += h2v * (double)W3[vv * 2 + 1];
    }

    const double G0 = __shfl(ga, 0);
    const double G1 = __shfl(ga, 1);
    if (lane == 0) {
      const bool one = (l0 + G0 >= l1 + G1);
      adj_bin[flat] = one ? (unsigned short)0x3F80u : (unsigned short)0u;
      if (one) atomicAdd(&rowsumF[flat >> 8], 1.0f);
    }
  }
}

// ---------------------------------------------------------------------------
// K3: fused output. Block = (z = bid&127, rowgroup rg = bid>>7 of 32 S-rows).
// Phase 1: X(32x256) = rs * (adj_rows @ F[z]) in regs (binA x 2-term B).
// Transition: X -> LDS as bf16 hi/lo (over Aadj region).
// Phase 2: out = X @ Wl + bl (3-term), A-frags from LDS.
// LDS: union(Aadj[32][264], Xh/Xl[32][264]) @0 (33792B), Bh/Bl[256][40] @33792.
// B staging: n = (tid&31) + 32*i, scalar coalesced loads (conflict-fixed).
// ---------------------------------------------------------------------------
__global__ __launch_bounds__(256) void fused_out_kernel(
    const unsigned short* __restrict__ adjp, const float* __restrict__ F,
    const float* __restrict__ Wl, const float* __restrict__ bl,
    const float* __restrict__ rowsumF, float* __restrict__ out) {
  extern __shared__ char smem[];
  short* Aadj = (short*)smem;               // [32][264] (phase 1)
  short* Xh = (short*)smem;                 // [32][264] (phase 2)
  short* Xl = Xh + 32 * 264;
  short* Bh = (short*)(smem + 33792);       // [256][40] (n-major, k minor)
  short* Bl = Bh + 256 * 40;

  const int bid = blockIdx.x;
  const int z = bid & 127;   // batch b*4+c; same-z blocks share bid%8 -> XCD
  const int rg = bid >> 7;   // 0..7
  const int b = z >> 2;
  const int row0 = rg * 32;

  const unsigned short* Ab = adjp + (size_t)b * 65536 + (size_t)row0 * 256;
  const float* Fb = F + (size_t)z * 65536;
  const float* rsb = rowsumF + b * 256 + row0;
  float* Ob = out + (size_t)z * 65536 + (size_t)row0 * 256;

  const int tid = threadIdx.x;
  const int w = tid >> 6;
  const int wc2 = w * 64;  // wave's 64 output cols
  const int lane = tid & 63;
  const int fcol = lane & 15;
  const int kg = lane >> 4;

  const int nlane = tid & 31;     // B staging: base row (lane stride 1 row)
  const int kb = (tid >> 5) * 4;  // B staging: 4 ks

  // stage adj rows (32x256 bf16, raw copy - binary values exact)
  {
    const int r = tid >> 3;
    const int c0 = (tid & 7) * 32;
#pragma unroll
    for (int q = 0; q < 4; ++q) {
      short8v v = *(const short8v*)(Ab + (size_t)r * 256 + c0 + q * 8);
      *(short8v*)&Aadj[r * 264 + c0 + q * 8] = v;
    }
  }

  float4v acc[2][4];
#pragma unroll
  for (int i = 0; i < 2; ++i)
#pragma unroll
    for (int j = 0; j < 4; ++j) acc[i][j] = (float4v)(0.0f);

  // ---- phase 1: acc = adj @ F ----
  for (int k0 = 0; k0 < 256; k0 += 32) {
    float fv[8][4];
#pragma unroll
    for (int i = 0; i < 8; ++i) {
      const int n = nlane + 32 * i;
#pragma unroll
      for (int j = 0; j < 4; ++j)
        fv[i][j] = Fb[(size_t)(k0 + kb + j) * 256 + n];
    }
    __syncthreads();  // fences Aadj staging (k0=0) and prior frag reads
#pragma unroll
    for (int i = 0; i < 8; ++i) {
      const int n = nlane + 32 * i;
      short h[4], l[4];
#pragma unroll
      for (int j = 0; j < 4; ++j) split_bf16(fv[i][j], h[j], l[j]);
      *(short4v*)&Bh[n * 40 + kb] = *(short4v*)&h[0];
      *(short4v*)&Bl[n * 40 + kb] = *(short4v*)&l[0];
    }
    __syncthreads();

    short8v af[2], bfh[4], bfl[4];
#pragma unroll
    for (int im = 0; im < 2; ++im)
      af[im] = *(const short8v*)&Aadj[(im * 16 + fcol) * 264 + k0 + kg * 8];
#pragma unroll
    for (int in = 0; in < 4; ++in) {
      bfh[in] = *(const short8v*)&Bh[(wc2 + in * 16 + fcol) * 40 + kg * 8];
      bfl[in] = *(const short8v*)&Bl[(wc2 + in * 16 + fcol) * 40 + kg * 8];
    }
#pragma unroll
    for (int im = 0; im < 2; ++im)
#pragma unroll
      for (int in = 0; in < 4; ++in) {
        acc[im][in] = __builtin_amdgcn_mfma_f32_16x16x32_bf16(
            af[im], bfh[in], acc[im][in], 0, 0, 0);
        acc[im][in] = __builtin_amdgcn_mfma_f32_16x16x32_bf16(
            af[im], bfl[in], acc[im][in], 0, 0, 0);
      }
  }

  // ---- transition: X = rs*acc -> LDS bf16 hi/lo (over Aadj) ----
  __syncthreads();  // all phase-1 LDS reads complete
  {
    float rsv[2][4];
#pragma unroll
    for (int im = 0; im < 2; ++im)
#pragma unroll
      for (int r = 0; r < 4; ++r)
        rsv[im][r] = 1.0f / rsb[im * 16 + kg * 4 + r];
#pragma unroll
    for (int im = 0; im < 2; ++im)
#pragma unroll
      for (int in = 0; in < 4; ++in) {
        const int col = wc2 + in * 16 + fcol;
#pragma unroll
        for (int r = 0; r < 4; ++r) {
          const int row = im * 16 + kg * 4 + r;
          short h, l;
          split_bf16(acc[im][in][r] * rsv[im][r], h, l);
          Xh[row * 264 + col] = h;
          Xl[row * 264 + col] = l;
        }
      }
  }
#pragma unroll
  for (int i = 0; i < 2; ++i)
#pragma unroll
    for (int j = 0; j < 4; ++j) acc[i][j] = (float4v)(0.0f);

  // ---- phase 2: out = X @ Wl + bl (3-term) ----
  for (int k0 = 0; k0 < 256; k0 += 32) {
    float fv[8][4];
#pragma unroll
    for (int i = 0; i < 8; ++i) {
      const int n = nlane + 32 * i;
#pragma unroll
      for (int j = 0; j < 4; ++j)
        fv[i][j] = Wl[(size_t)(k0 + kb + j) * 256 + n];
    }
    __syncthreads();  // fences X writes (k0=0) and prior frag reads
#pragma unroll
    for (int i = 0; i < 8; ++i) {
      const int n = nlane + 32 * i;
      short h[4], l[4];
#pragma unroll
      for (int j = 0; j < 4; ++j) split_bf16(fv[i][j], h[j], l[j]);
      *(short4v*)&Bh[n * 40 + kb] = *(short4v*)&h[0];
      *(short4v*)&Bl[n * 40 + kb] = *(short4v*)&l[0];
    }
    __syncthreads();

    short8v afh[2], afl[2], bfh[4], bfl[4];
#pragma unroll
    for (int im = 0; im < 2; ++im) {
      afh[im] = *(const short8v*)&Xh[(im * 16 + fcol) * 264 + k0 + kg * 8];
      afl[im] = *(const short8v*)&Xl[(im * 16 + fcol) * 264 + k0 + kg * 8];
    }
#pragma unroll
    for (int in = 0; in < 4; ++in) {
      bfh[in] = *(const short8v*)&Bh[(wc2 + in * 16 + fcol) * 40 + kg * 8];
      bfl[in] = *(const short8v*)&Bl[(wc2 + in * 16 + fcol) * 40 + kg * 8];
    }
#pragma unroll
    for (int im = 0; im < 2; ++im)
#pragma unroll
      for (int in = 0; in < 4; ++in) {
        acc[im][in] = __builtin_amdgcn_mfma_f32_16x16x32_bf16(
            afh[im], bfh[in], acc[im][in], 0, 0, 0);
        acc[im][in] = __builtin_amdgcn_mfma_f32_16x16x32_bf16(
            afh[im], bfl[in], acc[im][in], 0, 0, 0);
        acc[im][in] = __builtin_amdgcn_mfma_f32_16x16x32_bf16(
            afl[im], bfh[in], acc[im][in], 0, 0, 0);
      }
  }

  // ---- epilogue ----
#pragma unroll
  for (int in = 0; in < 4; ++in) {
    const int col = wc2 + in * 16 + fcol;
    const float bvx = bl[col];
#pragma unroll
    for (int im = 0; im < 2; ++im) {
      const int rbase = im * 16 + kg * 4;
#pragma unroll
      for (int r = 0; r < 4; ++r)
        Ob[(size_t)(rbase + r) * 256 + col] = acc[im][in][r] + bvx;
    }
  }
}

extern "C" void kernel_launch(void* const* d_in, const int* in_sizes, int n_in,
                              void* d_out, int out_size, void* d_ws,
                              size_t ws_size, hipStream_t stream) {
  const float* features = (const float*)d_in[0];
  const float* fm       = (const float*)d_in[1];
  const float* W1 = (const float*)d_in[2];
  const float* b1 = (const float*)d_in[3];
  const float* W2 = (const float*)d_in[4];
  const float* b2 = (const float*)d_in[5];
  const float* W3 = (const float*)d_in[6];
  const float* b3 = (const float*)d_in[7];
  const float* Wl = (const float*)d_in[8];
  const float* bl = (const float*)d_in[9];
  float* out = (float*)d_out;

  // ws layout:
  //   tbl      @ 0       .. 524KB
  //   rowsumF  @ 576KB   .. 608KB   (8192 f32)
  //   counter  @ 640KB   (4B), worklist follows (512KB)
  //   adj_bin  @ 2.0MB   .. 6.2MB   (bf16 ushort)
  //   corr     @ 10.5MB  .. 18.9MB  (f32, dead after decide_fast)
  char* ws = (char*)d_ws;
  float* tbl          = (float*)ws;
  float* rowsumF      = (float*)(ws + 576u * 1024u);
  uint32_t* counter   = (uint32_t*)(ws + 640u * 1024u);
  uint32_t* worklist  = counter + 16;
  unsigned short* adj = (unsigned short*)(ws + 2u * 1024u * 1024u);
  float* corr         = (float*)(ws + 10800u * 1024u);

  // allow >64KB dynamic LDS for the fused kernel (deterministic, idempotent)
  hipFuncSetAttribute((const void*)fused_out_kernel,
                      hipFuncAttributeMaxDynamicSharedMemorySize, FUSED_LDS);

  corr_table_kernel<<<dim3(641), 256, 0, stream>>>(fm, corr, W1, b1, W2, b2,
                                                   W3, b3, tbl, counter);
  decide_fast_kernel<<<dim3(8192), 256, 0, stream>>>(corr, tbl, adj, counter,
                                                     worklist, rowsumF);
  decide_exact_kernel<<<dim3(2048), 256, 0, stream>>>(fm, counter, worklist,
                                                      W1, b1, W2, b2, W3, b3,
                                                      adj, rowsumF);
  fused_out_kernel<<<dim3(1024), 256, FUSED_LDS, stream>>>(adj, features, Wl,
                                                           bl, rowsumF, out);
}

// Round 19
// 89.629 us; speedup vs baseline: 1.4259x; 1.1546x over previous
//
#include <hip/hip_runtime.h>
#include <stdint.h>

// ---------------------------------------------------------------------------
// B=32, C=4, S=256, L=256, Din=Dout=256
// Pipeline (5 dispatches) — round-15 structure (fused K3+K4 abandoned after
// 3 attempts: 32-row tile + 16 barriered k-steps is latency-bound regardless
// of bank conflicts), plus one bit-exact micro-opt:
//   K0 corr_table:  blocks 0..127: corr[b] = fm[b]@fm[b]^T (4-term bf16 MFMA)
//                   blocks 128..640: dphi table (131073 nodes) + counter zero
//   K1 decide_fast: one block = one adj row; lerp+gumbel32, dynamic guard
//                   thr = 4e-4 + slope*6e-4; adj bf16; fused rowsum
//   K2 decide_exact: ONE WAVE PER ITEM exact f64 (dot from fm + lane-parallel
//                   mlp64 + gumbel64); patches adj + rowsumF
//   K3 gemm_binA:   X = (1/rowsumF)*(adj @ F), output PRE-SPLIT as bf16
//                   hi/lo planes (split moved here from K4 - bit-identical)
//   K4 gemm_out:    out = X @ Wl + bl (3-term); A staged as raw bf16 copies
// threefry partitionable (jax key 42): bits(i) = o0^o1 of tf2x32((0,42),(0,i))
// ---------------------------------------------------------------------------

#define TBL_INTERVALS 131072
#define TBL_MIN -128.0f
#define TBL_SCALE 512.0f
#define WL_CAP 131072u

typedef __attribute__((ext_vector_type(8))) short short8v;
typedef __attribute__((ext_vector_type(4))) short short4v;
typedef __attribute__((ext_vector_type(4))) float float4v;

__device__ __forceinline__ void threefry2x32(uint32_t x0, uint32_t x1,
                                             uint32_t& o0, uint32_t& o1) {
  const uint32_t ks0 = 0u;
  const uint32_t ks1 = 42u;
  const uint32_t ks2 = 0x1BD11BDAu ^ ks0 ^ ks1;
  const uint32_t ks[3] = {ks0, ks1, ks2};
  const uint32_t rot[2][4] = {{13u, 15u, 26u, 6u}, {17u, 29u, 16u, 24u}};
  x0 += ks0;
  x1 += ks1;
#pragma unroll
  for (int i = 0; i < 5; ++i) {
#pragma unroll
    for (int j = 0; j < 4; ++j) {
      const uint32_t r = rot[i & 1][j];
      x0 += x1;
      x1 = (x1 << r) | (x1 >> (32u - r));
      x1 ^= x0;
    }
    x0 += ks[(i + 1) % 3];
    x1 += ks[(i + 2) % 3] + (uint32_t)(i + 1);
  }
  o0 = x0;
  o1 = x1;
}

__device__ __forceinline__ float uniform_at(uint32_t j) {
  uint32_t o0, o1;
  threefry2x32(0u, j, o0, o1);
  const uint32_t bits = o0 ^ o1;
  uint32_t fb = (bits >> 9) | 0x3F800000u;
  float frac = __uint_as_float(fb) - 1.0f;
  return fmaxf(frac + 1e-10f, 1e-10f);
}

__device__ __forceinline__ double gumbel64_at(uint32_t j) {
  double t = -log((double)uniform_at(j));
  return -log(t);
}

__device__ __forceinline__ float gumbel32_at(uint32_t j) {
  float t = -logf(uniform_at(j));
  return -logf(t);
}

__device__ __forceinline__ double gelu_d(double x) {
  return 0.5 * x * (1.0 + erf(x * 0.70710678118654752440));
}

__device__ __forceinline__ float gelu_f(float x) {
  return 0.5f * x * (1.0f + erff(x * 0.70710678f));
}

__device__ __forceinline__ float mlp32(float corr, const float* __restrict__ W1,
                                       const float* __restrict__ b1,
                                       const float* __restrict__ W2,
                                       const float* __restrict__ b2,
                                       const float* __restrict__ W3,
                                       const float* __restrict__ b3) {
  float h1[16];
#pragma unroll
  for (int u = 0; u < 16; ++u) h1[u] = gelu_f(fmaf(corr, W1[u], b1[u]));
  float h2[8];
#pragma unroll
  for (int v = 0; v < 8; ++v) {
    float x = b2[v];
#pragma unroll
    for (int u = 0; u < 16; ++u) x = fmaf(h1[u], W2[u * 8 + v], x);
    h2[v] = gelu_f(x);
  }
  float l0 = b3[0], l1 = b3[1];
#pragma unroll
  for (int v = 0; v < 8; ++v) {
    l0 = fmaf(h2[v], W3[v * 2 + 0], l0);
    l1 = fmaf(h2[v], W3[v * 2 + 1], l1);
  }
  return l0 - l1;
}

// RNE f32 -> bf16 split
__device__ __forceinline__ void split_bf16(float x, short& h, short& l) {
  uint32_t u = __float_as_uint(x);
  uint32_t hr = (u + 0x7FFFu + ((u >> 16) & 1u)) >> 16;
  float hf = __uint_as_float(hr << 16);
  float lo = x - hf;
  uint32_t v = __float_as_uint(lo);
  uint32_t lr = (v + 0x7FFFu + ((v >> 16) & 1u)) >> 16;
  h = (short)hr;
  l = (short)lr;
}

// ---------------------------------------------------------------------------
// K0: corr tiles (blocks 0..127) + dphi table (blocks 128..640) + counter.
// ---------------------------------------------------------------------------
__global__ __launch_bounds__(256) void corr_table_kernel(
    const float* __restrict__ fm, float* __restrict__ corr,
    const float* __restrict__ W1, const float* __restrict__ b1,
    const float* __restrict__ W2, const float* __restrict__ b2,
    const float* __restrict__ W3, const float* __restrict__ b3,
    float* __restrict__ tbl, uint32_t* __restrict__ counter) {
  if (blockIdx.x >= 128) {
    const int i = (int)(blockIdx.x - 128) * 256 + threadIdx.x;
    if (blockIdx.x == 128 && threadIdx.x == 0) counter[0] = 0u;
    if (i <= TBL_INTERVALS) {
      const float x = TBL_MIN + (float)i * (1.0f / TBL_SCALE);
      tbl[i] = mlp32(x, W1, b1, W2, b2, W3, b3);
    }
    return;
  }

  const int bid = blockIdx.x;
  const int b = bid >> 2;
  const int row0 = ((bid >> 1) & 1) * 128;
  const int col0 = (bid & 1) * 128;
  const float* base = fm + (size_t)b * 65536;

  __shared__ short Ah[128][40];
  __shared__ short Al[128][40];
  __shared__ short Bh[128][40];  // [n][k]
  __shared__ short Bl[128][40];

  const int tid = threadIdx.x;
  const int w = tid >> 6;
  const int wr = (w >> 1) * 64;
  const int wc = (w & 1) * 64;
  const int lane = tid & 63;
  const int fcol = lane & 15;
  const int kg = lane >> 4;

  const int am = tid >> 1;
  const int ak = (tid & 1) * 16;

  float4v acc[4][4];
#pragma unroll
  for (int i = 0; i < 4; ++i)
#pragma unroll
    for (int j = 0; j < 4; ++j) acc[i][j] = (float4v)(0.0f);

  for (int k0 = 0; k0 < 256; k0 += 32) {
    float4 av[4], bv[4];
#pragma unroll
    for (int q = 0; q < 4; ++q) {
      av[q] = *(const float4*)(base + (size_t)(row0 + am) * 256 + k0 + ak + q * 4);
      bv[q] = *(const float4*)(base + (size_t)(col0 + am) * 256 + k0 + ak + q * 4);
    }

    __syncthreads();

    {
      short h[16], l[16];
#pragma unroll
      for (int q = 0; q < 4; ++q) {
        split_bf16(av[q].x, h[q * 4 + 0], l[q * 4 + 0]);
        split_bf16(av[q].y, h[q * 4 + 1], l[q * 4 + 1]);
        split_bf16(av[q].z, h[q * 4 + 2], l[q * 4 + 2]);
        split_bf16(av[q].w, h[q * 4 + 3], l[q * 4 + 3]);
      }
      *(short8v*)&Ah[am][ak] = *(short8v*)&h[0];
      *(short8v*)&Ah[am][ak + 8] = *(short8v*)&h[8];
      *(short8v*)&Al[am][ak] = *(short8v*)&l[0];
      *(short8v*)&Al[am][ak + 8] = *(short8v*)&l[8];
#pragma unroll
      for (int q = 0; q < 4; ++q) {
        split_bf16(bv[q].x, h[q * 4 + 0], l[q * 4 + 0]);
        split_bf16(bv[q].y, h[q * 4 + 1], l[q * 4 + 1]);
        split_bf16(bv[q].z, h[q * 4 + 2], l[q * 4 + 2]);
        split_bf16(bv[q].w, h[q * 4 + 3], l[q * 4 + 3]);
      }
      *(short8v*)&Bh[am][ak] = *(short8v*)&h[0];
      *(short8v*)&Bh[am][ak + 8] = *(short8v*)&h[8];
      *(short8v*)&Bl[am][ak] = *(short8v*)&l[0];
      *(short8v*)&Bl[am][ak + 8] = *(short8v*)&l[8];
    }
    __syncthreads();

    short8v afh[4], afl[4], bfh[4], bfl[4];
#pragma unroll
    for (int im = 0; im < 4; ++im) {
      afh[im] = *(const short8v*)&Ah[wr + im * 16 + fcol][kg * 8];
      afl[im] = *(const short8v*)&Al[wr + im * 16 + fcol][kg * 8];
    }
#pragma unroll
    for (int in = 0; in < 4; ++in) {
      bfh[in] = *(const short8v*)&Bh[wc + in * 16 + fcol][kg * 8];
      bfl[in] = *(const short8v*)&Bl[wc + in * 16 + fcol][kg * 8];
    }
#pragma unroll
    for (int im = 0; im < 4; ++im)
#pragma unroll
      for (int in = 0; in < 4; ++in) {
        acc[im][in] = __builtin_amdgcn_mfma_f32_16x16x32_bf16(
            afh[im], bfh[in], acc[im][in], 0, 0, 0);
        acc[im][in] = __builtin_amdgcn_mfma_f32_16x16x32_bf16(
            afh[im], bfl[in], acc[im][in], 0, 0, 0);
        acc[im][in] = __builtin_amdgcn_mfma_f32_16x16x32_bf16(
            afl[im], bfh[in], acc[im][in], 0, 0, 0);
        acc[im][in] = __builtin_amdgcn_mfma_f32_16x16x32_bf16(
            afl[im], bfl[in], acc[im][in], 0, 0, 0);
      }
  }

  float* Cb = corr + (size_t)b * 65536;
#pragma unroll
  for (int in = 0; in < 4; ++in) {
    const int col = col0 + wc + in * 16 + fcol;
#pragma unroll
    for (int im = 0; im < 4; ++im) {
      const int rbase = row0 + wr + im * 16 + kg * 4;
#pragma unroll
      for (int r = 0; r < 4; ++r)
        Cb[(size_t)(rbase + r) * 256 + col] = acc[im][in][r];
    }
  }
}

// ---------------------------------------------------------------------------
// K1: decide_fast + fused rowsum. One block = one (b,s) row. grid 8192 x 256.
// ---------------------------------------------------------------------------
__global__ __launch_bounds__(256) void decide_fast_kernel(
    const float* __restrict__ corr, const float* __restrict__ tbl,
    unsigned short* __restrict__ adj_bin, uint32_t* __restrict__ counter,
    uint32_t* __restrict__ worklist, float* __restrict__ rowsumF) {
  const uint32_t flat = blockIdx.x * 256u + threadIdx.x;  // < 2,097,152
  const int t = threadIdx.x;
  const int s = blockIdx.x & 255;

  float a = 1.0f;
  bool pend = false;
  if (t != s) {
    const float cf = corr[flat];
    if (fabsf(cf) >= 127.0f) {
      pend = true;
      a = 0.0f;
    } else {
      const float xf = (cf - TBL_MIN) * TBL_SCALE;
      const int i = (int)xf;
      const float fr = xf - (float)i;
      const float t0v = tbl[i];
      const float t1v = tbl[i + 1];
      const float dt = t1v - t0v;
      const float dphi = fmaf(fr, dt, t0v);

      const float g0 = gumbel32_at(2u * flat);
      const float g1 = gumbel32_at(2u * flat + 1u);
      const float d = dphi - (g1 - g0);
      const float thr = fmaf(fabsf(dt), 0.3072f, 4e-4f);
      if (fabsf(d) >= thr) {
        a = (d >= 0.0f) ? 1.0f : 0.0f;
      } else {
        pend = true;
        a = 0.0f;
      }
    }
  }
  if (pend) {
    const uint32_t idx = atomicAdd(counter, 1u);
    if (idx < WL_CAP) worklist[idx] = flat;
  }
  adj_bin[flat] = (a == 1.0f) ? (unsigned short)0x3F80u : (unsigned short)0u;

  float sum = a;
#pragma unroll
  for (int off = 32; off; off >>= 1) sum += __shfl_xor(sum, off);
  __shared__ float red[4];
  if ((threadIdx.x & 63) == 0) red[threadIdx.x >> 6] = sum;
  __syncthreads();
  if (threadIdx.x == 0)
    rowsumF[blockIdx.x] = red[0] + red[1] + red[2] + red[3];
}

// ---------------------------------------------------------------------------
// K2: exact f64 resolve, ONE WAVE PER ITEM (validated path). grid 2048 x 256.
// ---------------------------------------------------------------------------
__global__ __launch_bounds__(256) void decide_exact_kernel(
    const float* __restrict__ fm, const uint32_t* __restrict__ counter,
    const uint32_t* __restrict__ worklist,
    const float* __restrict__ W1, const float* __restrict__ b1,
    const float* __restrict__ W2, const float* __restrict__ b2,
    const float* __restrict__ W3, const float* __restrict__ b3,
    unsigned short* __restrict__ adj_bin, float* __restrict__ rowsumF) {
  const uint32_t n = min(counter[0], WL_CAP);
  const uint32_t waveId = (blockIdx.x * 256u + threadIdx.x) >> 6;
  const uint32_t nWaves = (gridDim.x * 256u) >> 6;
  const int lane = threadIdx.x & 63;

  for (uint32_t it = waveId; it < n; it += nWaves) {
    const uint32_t flat = worklist[it];
    const uint32_t bb = flat >> 16;
    const uint32_t ss = (flat >> 8) & 255u;
    const uint32_t tt = flat & 255u;

    const float* S = fm + ((size_t)bb * 256 + ss) * 256;
    const float* T = fm + ((size_t)bb * 256 + tt) * 256;
    double p = 0.0;
#pragma unroll
    for (int q = 0; q < 4; ++q) {
      const int k = lane + q * 64;
      p += (double)S[k] * (double)T[k];
    }
#pragma unroll
    for (int off = 32; off; off >>= 1) p += __shfl_xor(p, off);
    const double acc = p;

    const double ga = gumbel64_at(2u * flat + (uint32_t)(lane & 1));

    const int u = lane & 15;
    const double h1 = gelu_d(acc * (double)W1[u] + (double)b1[u]);

    const int v = lane & 7;
    double sv = (double)b2[v];
#pragma unroll
    for (int uu = 0; uu < 16; ++uu) {
      const double h1u = __shfl(h1, uu);
      sv += h1u * (double)W2[uu * 8 + v];
    }
    const double h2 = gelu_d(sv);

    double l0 = (double)b3[0], l1 = (double)b3[1];
#pragma unroll
    for (int vv = 0; vv < 8; ++vv) {
      const double h2v = __shfl(h2, vv);
      l0 += h2v * (double)W3[vv * 2 + 0];
      l1 += h2v * (double)W3[vv * 2 + 1];
    }

    const double G0 = __shfl(ga, 0);
    const double G1 = __shfl(ga, 1);
    if (lane == 0) {
      const bool one = (l0 + G0 >= l1 + G1);
      adj_bin[flat] = one ? (unsigned short)0x3F80u : (unsigned short)0u;
      if (one) atomicAdd(&rowsumF[flat >> 8], 1.0f);
    }
  }
}

// ---------------------------------------------------------------------------
// K3: X = (1/rowsumF)*(adj @ F), OUTPUT PRE-SPLIT as bf16 hi/lo planes.
// A raw bf16 (exact binary), B split hi+lo (2-term) -> 32 MFMA / K-step.
// ---------------------------------------------------------------------------
__global__ __launch_bounds__(256) void gemm_binA_kernel(
    const unsigned short* __restrict__ A, const float* __restrict__ B,
    const float* __restrict__ rowsumF, unsigned short* __restrict__ Xh_g,
    unsigned short* __restrict__ Xl_g) {
  const int z = blockIdx.z;
  const unsigned short* Ab = A + (size_t)(z / 4) * 65536;
  const float* Bb = B + (size_t)z * 65536;
  const float* rsb = rowsumF + (size_t)(z / 4) * 256;
  unsigned short* Xhb = Xh_g + (size_t)z * 65536;
  unsigned short* Xlb = Xl_g + (size_t)z * 65536;

  const int row0 = blockIdx.y * 128;
  const int col0 = blockIdx.x * 128;

  __shared__ short Ah[128][40];
  __shared__ short Bh[128][40];  // [n][k]
  __shared__ short Bl[128][40];

  const int tid = threadIdx.x;
  const int w = tid >> 6;
  const int wr = (w >> 1) * 64;
  const int wc = (w & 1) * 64;
  const int lane = tid & 63;
  const int fcol = lane & 15;
  const int kg = lane >> 4;

  const int am = tid >> 1;
  const int ak = (tid & 1) * 16;
  const int nq = (tid & 31) * 4;
  const int kb = (tid >> 5) * 4;

  float4v acc[4][4];
#pragma unroll
  for (int i = 0; i < 4; ++i)
#pragma unroll
    for (int j = 0; j < 4; ++j) acc[i][j] = (float4v)(0.0f);

  for (int k0 = 0; k0 < 256; k0 += 32) {
    short8v a0 = *(const short8v*)(Ab + (size_t)(row0 + am) * 256 + k0 + ak);
    short8v a1 = *(const short8v*)(Ab + (size_t)(row0 + am) * 256 + k0 + ak + 8);
    float4 bv[4];
#pragma unroll
    for (int j = 0; j < 4; ++j)
      bv[j] = *(const float4*)(Bb + (size_t)(k0 + kb + j) * 256 + col0 + nq);

    __syncthreads();

    *(short8v*)&Ah[am][ak] = a0;
    *(short8v*)&Ah[am][ak + 8] = a1;
    {
      const float bm[4][4] = {{bv[0].x, bv[1].x, bv[2].x, bv[3].x},
                              {bv[0].y, bv[1].y, bv[2].y, bv[3].y},
                              {bv[0].z, bv[1].z, bv[2].z, bv[3].z},
                              {bv[0].w, bv[1].w, bv[2].w, bv[3].w}};
#pragma unroll
      for (int i = 0; i < 4; ++i) {
        short h[4], l[4];
#pragma unroll
        for (int j = 0; j < 4; ++j) split_bf16(bm[i][j], h[j], l[j]);
        *(short4v*)&Bh[nq + i][kb] = *(short4v*)&h[0];
        *(short4v*)&Bl[nq + i][kb] = *(short4v*)&l[0];
      }
    }
    __syncthreads();

    short8v afh[4], bfh[4], bfl[4];
#pragma unroll
    for (int im = 0; im < 4; ++im)
      afh[im] = *(const short8v*)&Ah[wr + im * 16 + fcol][kg * 8];
#pragma unroll
    for (int in = 0; in < 4; ++in) {
      bfh[in] = *(const short8v*)&Bh[wc + in * 16 + fcol][kg * 8];
      bfl[in] = *(const short8v*)&Bl[wc + in * 16 + fcol][kg * 8];
    }
#pragma unroll
    for (int im = 0; im < 4; ++im)
#pragma unroll
      for (int in = 0; in < 4; ++in) {
        acc[im][in] = __builtin_amdgcn_mfma_f32_16x16x32_bf16(
            afh[im], bfh[in], acc[im][in], 0, 0, 0);
        acc[im][in] = __builtin_amdgcn_mfma_f32_16x16x32_bf16(
            afh[im], bfl[in], acc[im][in], 0, 0, 0);
      }
  }

#pragma unroll
  for (int im = 0; im < 4; ++im) {
    const int rbase = row0 + wr + im * 16 + kg * 4;
    float rsv[4];
#pragma unroll
    for (int r = 0; r < 4; ++r) rsv[r] = 1.0f / rsb[rbase + r];
#pragma unroll
    for (int in = 0; in < 4; ++in) {
      const int col = col0 + wc + in * 16 + fcol;
#pragma unroll
      for (int r = 0; r < 4; ++r) {
        short h, l;
        split_bf16(acc[im][in][r] * rsv[r], h, l);
        Xhb[(size_t)(rbase + r) * 256 + col] = (unsigned short)h;
        Xlb[(size_t)(rbase + r) * 256 + col] = (unsigned short)l;
      }
    }
  }
}

// ---------------------------------------------------------------------------
// K4: out = X @ Wl + bl. A pre-split (raw bf16 copies), B split (3-term).
// ---------------------------------------------------------------------------
__global__ __launch_bounds__(256) void gemm_out_kernel(
    const unsigned short* __restrict__ Xh_g,
    const unsigned short* __restrict__ Xl_g, const float* __restrict__ B,
    const float* __restrict__ bias, float* __restrict__ C) {
  const int z = blockIdx.z;
  const unsigned short* Ahb = Xh_g + (size_t)z * 65536;
  const unsigned short* Alb = Xl_g + (size_t)z * 65536;
  const float* Bb = B;  // shared Wl
  float* Cb = C + (size_t)z * 65536;

  const int row0 = blockIdx.y * 128;
  const int col0 = blockIdx.x * 128;

  __shared__ short Ah[128][40];
  __shared__ short Al[128][40];
  __shared__ short Bh[128][40];
  __shared__ short Bl[128][40];

  const int tid = threadIdx.x;
  const int w = tid >> 6;
  const int wr = (w >> 1) * 64;
  const int wc = (w & 1) * 64;
  const int lane = tid & 63;
  const int fcol = lane & 15;
  const int kg = lane >> 4;

  const int am = tid >> 1;
  const int ak = (tid & 1) * 16;
  const int nq = (tid & 31) * 4;
  const int kb = (tid >> 5) * 4;

  float4v acc[4][4];
#pragma unroll
  for (int i = 0; i < 4; ++i)
#pragma unroll
    for (int j = 0; j < 4; ++j) acc[i][j] = (float4v)(0.0f);

  for (int k0 = 0; k0 < 256; k0 += 32) {
    short8v ah0 = *(const short8v*)(Ahb + (size_t)(row0 + am) * 256 + k0 + ak);
    short8v ah1 = *(const short8v*)(Ahb + (size_t)(row0 + am) * 256 + k0 + ak + 8);
    short8v al0 = *(const short8v*)(Alb + (size_t)(row0 + am) * 256 + k0 + ak);
    short8v al1 = *(const short8v*)(Alb + (size_t)(row0 + am) * 256 + k0 + ak + 8);
    float4 bv[4];
#pragma unroll
    for (int j = 0; j < 4; ++j)
      bv[j] = *(const float4*)(Bb + (size_t)(k0 + kb + j) * 256 + col0 + nq);

    __syncthreads();

    *(short8v*)&Ah[am][ak] = ah0;
    *(short8v*)&Ah[am][ak + 8] = ah1;
    *(short8v*)&Al[am][ak] = al0;
    *(short8v*)&Al[am][ak + 8] = al1;
    {
      const float bm[4][4] = {{bv[0].x, bv[1].x, bv[2].x, bv[3].x},
                              {bv[0].y, bv[1].y, bv[2].y, bv[3].y},
                              {bv[0].z, bv[1].z, bv[2].z, bv[3].z},
                              {bv[0].w, bv[1].w, bv[2].w, bv[3].w}};
#pragma unroll
      for (int i = 0; i < 4; ++i) {
        short h[4], l[4];
#pragma unroll
        for (int j = 0; j < 4; ++j) split_bf16(bm[i][j], h[j], l[j]);
        *(short4v*)&Bh[nq + i][kb] = *(short4v*)&h[0];
        *(short4v*)&Bl[nq + i][kb] = *(short4v*)&l[0];
      }
    }
    __syncthreads();

    short8v afh[4], afl[4], bfh[4], bfl[4];
#pragma unroll
    for (int im = 0; im < 4; ++im) {
      afh[im] = *(const short8v*)&Ah[wr + im * 16 + fcol][kg * 8];
      afl[im] = *(const short8v*)&Al[wr + im * 16 + fcol][kg * 8];
    }
#pragma unroll
    for (int in = 0; in < 4; ++in) {
      bfh[in] = *(const short8v*)&Bh[wc + in * 16 + fcol][kg * 8];
      bfl[in] = *(const short8v*)&Bl[wc + in * 16 + fcol][kg * 8];
    }
#pragma unroll
    for (int im = 0; im < 4; ++im)
#pragma unroll
      for (int in = 0; in < 4; ++in) {
        acc[im][in] = __builtin_amdgcn_mfma_f32_16x16x32_bf16(
            afh[im], bfh[in], acc[im][in], 0, 0, 0);
        acc[im][in] = __builtin_amdgcn_mfma_f32_16x16x32_bf16(
            afh[im], bfl[in], acc[im][in], 0, 0, 0);
        acc[im][in] = __builtin_amdgcn_mfma_f32_16x16x32_bf16(
            afl[im], bfh[in], acc[im][in], 0, 0, 0);
      }
  }

#pragma unroll
  for (int in = 0; in < 4; ++in) {
    const int col = col0 + wc + in * 16 + fcol;
    const float bvx = bias[col];
#pragma unroll
    for (int im = 0; im < 4; ++im) {
      const int rbase = row0 + wr + im * 16 + kg * 4;
#pragma unroll
      for (int r = 0; r < 4; ++r)
        Cb[(size_t)(rbase + r) * 256 + col] = acc[im][in][r] + bvx;
    }
  }
}

extern "C" void kernel_launch(void* const* d_in, const int* in_sizes, int n_in,
                              void* d_out, int out_size, void* d_ws,
                              size_t ws_size, hipStream_t stream) {
  const float* features = (const float*)d_in[0];
  const float* fm       = (const float*)d_in[1];
  const float* W1 = (const float*)d_in[2];
  const float* b1 = (const float*)d_in[3];
  const float* W2 = (const float*)d_in[4];
  const float* b2 = (const float*)d_in[5];
  const float* W3 = (const float*)d_in[6];
  const float* b3 = (const float*)d_in[7];
  const float* Wl = (const float*)d_in[8];
  const float* bl = (const float*)d_in[9];
  float* out = (float*)d_out;

  // ws layout (44.1 MB):
  //   tbl      @ 0       .. 524KB
  //   rowsumF  @ 576KB   .. 608KB   (8192 f32)
  //   counter  @ 640KB   (4B), worklist follows (512KB)
  //   adj_bin  @ 2.0MB   .. 6.2MB   (bf16 ushort)
  //   corr     @ 10.5MB  .. 18.9MB  (f32, dead after decide_fast)
  //   Xh       @ 10.5MB  .. 27.3MB  (bf16 hi plane, overwrites corr - safe)
  //   Xl       @ 27.3MB  .. 44.1MB  (bf16 lo plane)
  char* ws = (char*)d_ws;
  float* tbl          = (float*)ws;
  float* rowsumF      = (float*)(ws + 576u * 1024u);
  uint32_t* counter   = (uint32_t*)(ws + 640u * 1024u);
  uint32_t* worklist  = counter + 16;
  unsigned short* adj = (unsigned short*)(ws + 2u * 1024u * 1024u);
  float* corr         = (float*)(ws + 10800u * 1024u);
  unsigned short* Xh  = (unsigned short*)(ws + 10800u * 1024u);
  unsigned short* Xl  = (unsigned short*)(ws + 10800u * 1024u + 16777216u);

  corr_table_kernel<<<dim3(641), 256, 0, stream>>>(fm, corr, W1, b1, W2, b2,
                                                   W3, b3, tbl, counter);
  decide_fast_kernel<<<dim3(8192), 256, 0, stream>>>(corr, tbl, adj, counter,
                                                     worklist, rowsumF);
  decide_exact_kernel<<<dim3(2048), 256, 0, stream>>>(fm, counter, worklist,
                                                      W1, b1, W2, b2, W3, b3,
                                                      adj, rowsumF);
  // X = (1/rowsum)*(adj @ F), pre-split output (Xh overwrites corr - consumed)
  gemm_binA_kernel<<<dim3(2, 2, 128), 256, 0, stream>>>(adj, features,
                                                        rowsumF, Xh, Xl);
  // out = X @ Wl + bl
  gemm_out_kernel<<<dim3(2, 2, 128), 256, 0, stream>>>(Xh, Xl, Wl, bl, out);
}

// Round 20
// 82.448 us; speedup vs baseline: 1.5501x; 1.0871x over previous
//
#include <hip/hip_runtime.h>
#include <stdint.h>

// ---------------------------------------------------------------------------
// B=32, C=4, S=256, L=256, Din=Dout=256
// Pipeline (5 dispatches) — round-15 structure + measured bank-conflict fix:
//   K0 corr_table:  blocks 0..127: corr[b] = fm[b]@fm[b]^T (4-term bf16 MFMA)
//                   blocks 128..640: dphi table (131073 nodes) + counter zero
//   K1 decide_fast: one block = one adj row; lerp+gumbel32, dynamic guard
//                   thr = 4e-4 + slope*6e-4; adj bf16; fused rowsum
//   K2 decide_exact: ONE WAVE PER ITEM exact f64 (dot from fm + lane-parallel
//                   mlp64 + gumbel64); patches adj + rowsumF
//   K3 gemm_binA:   X = (1/rowsumF)*(adj @ F)  (f32 out, as round 15)
//   K4 gemm_mfma:   out = X @ Wl + bl (bf16x3, 3-term)
// FIX (measured r19: 4.7M conflicts in gemm_binA): B-staging lane->row stride
// was 4 rows (320B = 16 dw mod 32 -> 64 lanes on 4 banks, 16-way). Now
// n = (tid&31) + 32*i (stride 1 row = 20 dw -> 4-way); scalar coalesced
// loads; LDS contents identical -> bit-exact.
// threefry partitionable (jax key 42): bits(i) = o0^o1 of tf2x32((0,42),(0,i))
// ---------------------------------------------------------------------------

#define TBL_INTERVALS 131072
#define TBL_MIN -128.0f
#define TBL_SCALE 512.0f
#define WL_CAP 131072u

typedef __attribute__((ext_vector_type(8))) short short8v;
typedef __attribute__((ext_vector_type(4))) short short4v;
typedef __attribute__((ext_vector_type(4))) float float4v;

__device__ __forceinline__ void threefry2x32(uint32_t x0, uint32_t x1,
                                             uint32_t& o0, uint32_t& o1) {
  const uint32_t ks0 = 0u;
  const uint32_t ks1 = 42u;
  const uint32_t ks2 = 0x1BD11BDAu ^ ks0 ^ ks1;
  const uint32_t ks[3] = {ks0, ks1, ks2};
  const uint32_t rot[2][4] = {{13u, 15u, 26u, 6u}, {17u, 29u, 16u, 24u}};
  x0 += ks0;
  x1 += ks1;
#pragma unroll
  for (int i = 0; i < 5; ++i) {
#pragma unroll
    for (int j = 0; j < 4; ++j) {
      const uint32_t r = rot[i & 1][j];
      x0 += x1;
      x1 = (x1 << r) | (x1 >> (32u - r));
      x1 ^= x0;
    }
    x0 += ks[(i + 1) % 3];
    x1 += ks[(i + 2) % 3] + (uint32_t)(i + 1);
  }
  o0 = x0;
  o1 = x1;
}

__device__ __forceinline__ float uniform_at(uint32_t j) {
  uint32_t o0, o1;
  threefry2x32(0u, j, o0, o1);
  const uint32_t bits = o0 ^ o1;
  uint32_t fb = (bits >> 9) | 0x3F800000u;
  float frac = __uint_as_float(fb) - 1.0f;
  return fmaxf(frac + 1e-10f, 1e-10f);
}

__device__ __forceinline__ double gumbel64_at(uint32_t j) {
  double t = -log((double)uniform_at(j));
  return -log(t);
}

__device__ __forceinline__ float gumbel32_at(uint32_t j) {
  float t = -logf(uniform_at(j));
  return -logf(t);
}

__device__ __forceinline__ double gelu_d(double x) {
  return 0.5 * x * (1.0 + erf(x * 0.70710678118654752440));
}

__device__ __forceinline__ float gelu_f(float x) {
  return 0.5f * x * (1.0f + erff(x * 0.70710678f));
}

__device__ __forceinline__ float mlp32(float corr, const float* __restrict__ W1,
                                       const float* __restrict__ b1,
                                       const float* __restrict__ W2,
                                       const float* __restrict__ b2,
                                       const float* __restrict__ W3,
                                       const float* __restrict__ b3) {
  float h1[16];
#pragma unroll
  for (int u = 0; u < 16; ++u) h1[u] = gelu_f(fmaf(corr, W1[u], b1[u]));
  float h2[8];
#pragma unroll
  for (int v = 0; v < 8; ++v) {
    float x = b2[v];
#pragma unroll
    for (int u = 0; u < 16; ++u) x = fmaf(h1[u], W2[u * 8 + v], x);
    h2[v] = gelu_f(x);
  }
  float l0 = b3[0], l1 = b3[1];
#pragma unroll
  for (int v = 0; v < 8; ++v) {
    l0 = fmaf(h2[v], W3[v * 2 + 0], l0);
    l1 = fmaf(h2[v], W3[v * 2 + 1], l1);
  }
  return l0 - l1;
}

// RNE f32 -> bf16 split
__device__ __forceinline__ void split_bf16(float x, short& h, short& l) {
  uint32_t u = __float_as_uint(x);
  uint32_t hr = (u + 0x7FFFu + ((u >> 16) & 1u)) >> 16;
  float hf = __uint_as_float(hr << 16);
  float lo = x - hf;
  uint32_t v = __float_as_uint(lo);
  uint32_t lr = (v + 0x7FFFu + ((v >> 16) & 1u)) >> 16;
  h = (short)hr;
  l = (short)lr;
}

// ---------------------------------------------------------------------------
// K0: corr tiles (blocks 0..127) + dphi table (blocks 128..640) + counter.
// ---------------------------------------------------------------------------
__global__ __launch_bounds__(256) void corr_table_kernel(
    const float* __restrict__ fm, float* __restrict__ corr,
    const float* __restrict__ W1, const float* __restrict__ b1,
    const float* __restrict__ W2, const float* __restrict__ b2,
    const float* __restrict__ W3, const float* __restrict__ b3,
    float* __restrict__ tbl, uint32_t* __restrict__ counter) {
  if (blockIdx.x >= 128) {
    const int i = (int)(blockIdx.x - 128) * 256 + threadIdx.x;
    if (blockIdx.x == 128 && threadIdx.x == 0) counter[0] = 0u;
    if (i <= TBL_INTERVALS) {
      const float x = TBL_MIN + (float)i * (1.0f / TBL_SCALE);
      tbl[i] = mlp32(x, W1, b1, W2, b2, W3, b3);
    }
    return;
  }

  const int bid = blockIdx.x;
  const int b = bid >> 2;
  const int row0 = ((bid >> 1) & 1) * 128;
  const int col0 = (bid & 1) * 128;
  const float* base = fm + (size_t)b * 65536;

  __shared__ short Ah[128][40];
  __shared__ short Al[128][40];
  __shared__ short Bh[128][40];  // [n][k]
  __shared__ short Bl[128][40];

  const int tid = threadIdx.x;
  const int w = tid >> 6;
  const int wr = (w >> 1) * 64;
  const int wc = (w & 1) * 64;
  const int lane = tid & 63;
  const int fcol = lane & 15;
  const int kg = lane >> 4;

  const int am = tid >> 1;
  const int ak = (tid & 1) * 16;

  float4v acc[4][4];
#pragma unroll
  for (int i = 0; i < 4; ++i)
#pragma unroll
    for (int j = 0; j < 4; ++j) acc[i][j] = (float4v)(0.0f);

  for (int k0 = 0; k0 < 256; k0 += 32) {
    float4 av[4], bv[4];
#pragma unroll
    for (int q = 0; q < 4; ++q) {
      av[q] = *(const float4*)(base + (size_t)(row0 + am) * 256 + k0 + ak + q * 4);
      bv[q] = *(const float4*)(base + (size_t)(col0 + am) * 256 + k0 + ak + q * 4);
    }

    __syncthreads();

    {
      short h[16], l[16];
#pragma unroll
      for (int q = 0; q < 4; ++q) {
        split_bf16(av[q].x, h[q * 4 + 0], l[q * 4 + 0]);
        split_bf16(av[q].y, h[q * 4 + 1], l[q * 4 + 1]);
        split_bf16(av[q].z, h[q * 4 + 2], l[q * 4 + 2]);
        split_bf16(av[q].w, h[q * 4 + 3], l[q * 4 + 3]);
      }
      *(short8v*)&Ah[am][ak] = *(short8v*)&h[0];
      *(short8v*)&Ah[am][ak + 8] = *(short8v*)&h[8];
      *(short8v*)&Al[am][ak] = *(short8v*)&l[0];
      *(short8v*)&Al[am][ak + 8] = *(short8v*)&l[8];
#pragma unroll
      for (int q = 0; q < 4; ++q) {
        split_bf16(bv[q].x, h[q * 4 + 0], l[q * 4 + 0]);
        split_bf16(bv[q].y, h[q * 4 + 1], l[q * 4 + 1]);
        split_bf16(bv[q].z, h[q * 4 + 2], l[q * 4 + 2]);
        split_bf16(bv[q].w, h[q * 4 + 3], l[q * 4 + 3]);
      }
      *(short8v*)&Bh[am][ak] = *(short8v*)&h[0];
      *(short8v*)&Bh[am][ak + 8] = *(short8v*)&h[8];
      *(short8v*)&Bl[am][ak] = *(short8v*)&l[0];
      *(short8v*)&Bl[am][ak + 8] = *(short8v*)&l[8];
    }
    __syncthreads();

    short8v afh[4], afl[4], bfh[4], bfl[4];
#pragma unroll
    for (int im = 0; im < 4; ++im) {
      afh[im] = *(const short8v*)&Ah[wr + im * 16 + fcol][kg * 8];
      afl[im] = *(const short8v*)&Al[wr + im * 16 + fcol][kg * 8];
    }
#pragma unroll
    for (int in = 0; in < 4; ++in) {
      bfh[in] = *(const short8v*)&Bh[wc + in * 16 + fcol][kg * 8];
      bfl[in] = *(const short8v*)&Bl[wc + in * 16 + fcol][kg * 8];
    }
#pragma unroll
    for (int im = 0; im < 4; ++im)
#pragma unroll
      for (int in = 0; in < 4; ++in) {
        acc[im][in] = __builtin_amdgcn_mfma_f32_16x16x32_bf16(
            afh[im], bfh[in], acc[im][in], 0, 0, 0);
        acc[im][in] = __builtin_amdgcn_mfma_f32_16x16x32_bf16(
            afh[im], bfl[in], acc[im][in], 0, 0, 0);
        acc[im][in] = __builtin_amdgcn_mfma_f32_16x16x32_bf16(
            afl[im], bfh[in], acc[im][in], 0, 0, 0);
        acc[im][in] = __builtin_amdgcn_mfma_f32_16x16x32_bf16(
            afl[im], bfl[in], acc[im][in], 0, 0, 0);
      }
  }

  float* Cb = corr + (size_t)b * 65536;
#pragma unroll
  for (int in = 0; in < 4; ++in) {
    const int col = col0 + wc + in * 16 + fcol;
#pragma unroll
    for (int im = 0; im < 4; ++im) {
      const int rbase = row0 + wr + im * 16 + kg * 4;
#pragma unroll
      for (int r = 0; r < 4; ++r)
        Cb[(size_t)(rbase + r) * 256 + col] = acc[im][in][r];
    }
  }
}

// ---------------------------------------------------------------------------
// K1: decide_fast + fused rowsum. One block = one (b,s) row. grid 8192 x 256.
// ---------------------------------------------------------------------------
__global__ __launch_bounds__(256) void decide_fast_kernel(
    const float* __restrict__ corr, const float* __restrict__ tbl,
    unsigned short* __restrict__ adj_bin, uint32_t* __restrict__ counter,
    uint32_t* __restrict__ worklist, float* __restrict__ rowsumF) {
  const uint32_t flat = blockIdx.x * 256u + threadIdx.x;  // < 2,097,152
  const int t = threadIdx.x;
  const int s = blockIdx.x & 255;

  float a = 1.0f;
  bool pend = false;
  if (t != s) {
    const float cf = corr[flat];
    if (fabsf(cf) >= 127.0f) {
      pend = true;
      a = 0.0f;
    } else {
      const float xf = (cf - TBL_MIN) * TBL_SCALE;
      const int i = (int)xf;
      const float fr = xf - (float)i;
      const float t0v = tbl[i];
      const float t1v = tbl[i + 1];
      const float dt = t1v - t0v;
      const float dphi = fmaf(fr, dt, t0v);

      const float g0 = gumbel32_at(2u * flat);
      const float g1 = gumbel32_at(2u * flat + 1u);
      const float d = dphi - (g1 - g0);
      const float thr = fmaf(fabsf(dt), 0.3072f, 4e-4f);
      if (fabsf(d) >= thr) {
        a = (d >= 0.0f) ? 1.0f : 0.0f;
      } else {
        pend = true;
        a = 0.0f;
      }
    }
  }
  if (pend) {
    const uint32_t idx = atomicAdd(counter, 1u);
    if (idx < WL_CAP) worklist[idx] = flat;
  }
  adj_bin[flat] = (a == 1.0f) ? (unsigned short)0x3F80u : (unsigned short)0u;

  float sum = a;
#pragma unroll
  for (int off = 32; off; off >>= 1) sum += __shfl_xor(sum, off);
  __shared__ float red[4];
  if ((threadIdx.x & 63) == 0) red[threadIdx.x >> 6] = sum;
  __syncthreads();
  if (threadIdx.x == 0)
    rowsumF[blockIdx.x] = red[0] + red[1] + red[2] + red[3];
}

// ---------------------------------------------------------------------------
// K2: exact f64 resolve, ONE WAVE PER ITEM (validated path). grid 2048 x 256.
// ---------------------------------------------------------------------------
__global__ __launch_bounds__(256) void decide_exact_kernel(
    const float* __restrict__ fm, const uint32_t* __restrict__ counter,
    const uint32_t* __restrict__ worklist,
    const float* __restrict__ W1, const float* __restrict__ b1,
    const float* __restrict__ W2, const float* __restrict__ b2,
    const float* __restrict__ W3, const float* __restrict__ b3,
    unsigned short* __restrict__ adj_bin, float* __restrict__ rowsumF) {
  const uint32_t n = min(counter[0], WL_CAP);
  const uint32_t waveId = (blockIdx.x * 256u + threadIdx.x) >> 6;
  const uint32_t nWaves = (gridDim.x * 256u) >> 6;
  const int lane = threadIdx.x & 63;

  for (uint32_t it = waveId; it < n; it += nWaves) {
    const uint32_t flat = worklist[it];
    const uint32_t bb = flat >> 16;
    const uint32_t ss = (flat >> 8) & 255u;
    const uint32_t tt = flat & 255u;

    const float* S = fm + ((size_t)bb * 256 + ss) * 256;
    const float* T = fm + ((size_t)bb * 256 + tt) * 256;
    double p = 0.0;
#pragma unroll
    for (int q = 0; q < 4; ++q) {
      const int k = lane + q * 64;
      p += (double)S[k] * (double)T[k];
    }
#pragma unroll
    for (int off = 32; off; off >>= 1) p += __shfl_xor(p, off);
    const double acc = p;

    const double ga = gumbel64_at(2u * flat + (uint32_t)(lane & 1));

    const int u = lane & 15;
    const double h1 = gelu_d(acc * (double)W1[u] + (double)b1[u]);

    const int v = lane & 7;
    double sv = (double)b2[v];
#pragma unroll
    for (int uu = 0; uu < 16; ++uu) {
      const double h1u = __shfl(h1, uu);
      sv += h1u * (double)W2[uu * 8 + v];
    }
    const double h2 = gelu_d(sv);

    double l0 = (double)b3[0], l1 = (double)b3[1];
#pragma unroll
    for (int vv = 0; vv < 8; ++vv) {
      const double h2v = __shfl(h2, vv);
      l0 += h2v * (double)W3[vv * 2 + 0];
      l1 += h2v * (double)W3[vv * 2 + 1];
    }

    const double G0 = __shfl(ga, 0);
    const double G1 = __shfl(ga, 1);
    if (lane == 0) {
      const bool one = (l0 + G0 >= l1 + G1);
      adj_bin[flat] = one ? (unsigned short)0x3F80u : (unsigned short)0u;
      if (one) atomicAdd(&rowsumF[flat >> 8], 1.0f);
    }
  }
}

// ---------------------------------------------------------------------------
// K3: X[b,c] = (1/rowsumF) * (adj[b] @ F[b,c]). A raw bf16 (exact binary),
// B split hi+lo (2-term). B staged with lane-stride-1 mapping (4-way banks).
// ---------------------------------------------------------------------------
__global__ __launch_bounds__(256) void gemm_binA_kernel(
    const unsigned short* __restrict__ A, const float* __restrict__ B,
    const float* __restrict__ rowsumF, float* __restrict__ C) {
  const int z = blockIdx.z;
  const unsigned short* Ab = A + (size_t)(z / 4) * 65536;
  const float* Bb = B + (size_t)z * 65536;
  const float* rsb = rowsumF + (size_t)(z / 4) * 256;
  float* Cb = C + (size_t)z * 65536;

  const int row0 = blockIdx.y * 128;
  const int col0 = blockIdx.x * 128;

  __shared__ short Ah[128][40];
  __shared__ short Bh[128][40];  // [n][k]
  __shared__ short Bl[128][40];

  const int tid = threadIdx.x;
  const int w = tid >> 6;
  const int wr = (w >> 1) * 64;
  const int wc = (w & 1) * 64;
  const int lane = tid & 63;
  const int fcol = lane & 15;
  const int kg = lane >> 4;

  const int am = tid >> 1;
  const int ak = (tid & 1) * 16;
  const int nlane = tid & 31;     // B staging: base col (lane stride 1 row)
  const int kb = (tid >> 5) * 4;  // B staging: 4 ks

  float4v acc[4][4];
#pragma unroll
  for (int i = 0; i < 4; ++i)
#pragma unroll
    for (int j = 0; j < 4; ++j) acc[i][j] = (float4v)(0.0f);

  for (int k0 = 0; k0 < 256; k0 += 32) {
    short8v a0 = *(const short8v*)(Ab + (size_t)(row0 + am) * 256 + k0 + ak);
    short8v a1 = *(const short8v*)(Ab + (size_t)(row0 + am) * 256 + k0 + ak + 8);
    float fv[4][4];
#pragma unroll
    for (int i = 0; i < 4; ++i) {
      const int n = nlane + 32 * i;
#pragma unroll
      for (int j = 0; j < 4; ++j)
        fv[i][j] = Bb[(size_t)(k0 + kb + j) * 256 + col0 + n];
    }

    __syncthreads();

    *(short8v*)&Ah[am][ak] = a0;
    *(short8v*)&Ah[am][ak + 8] = a1;
#pragma unroll
    for (int i = 0; i < 4; ++i) {
      const int n = nlane + 32 * i;
      short h[4], l[4];
#pragma unroll
      for (int j = 0; j < 4; ++j) split_bf16(fv[i][j], h[j], l[j]);
      *(short4v*)&Bh[n][kb] = *(short4v*)&h[0];
      *(short4v*)&Bl[n][kb] = *(short4v*)&l[0];
    }
    __syncthreads();

    short8v afh[4], bfh[4], bfl[4];
#pragma unroll
    for (int im = 0; im < 4; ++im)
      afh[im] = *(const short8v*)&Ah[wr + im * 16 + fcol][kg * 8];
#pragma unroll
    for (int in = 0; in < 4; ++in) {
      bfh[in] = *(const short8v*)&Bh[wc + in * 16 + fcol][kg * 8];
      bfl[in] = *(const short8v*)&Bl[wc + in * 16 + fcol][kg * 8];
    }
#pragma unroll
    for (int im = 0; im < 4; ++im)
#pragma unroll
      for (int in = 0; in < 4; ++in) {
        acc[im][in] = __builtin_amdgcn_mfma_f32_16x16x32_bf16(
            afh[im], bfh[in], acc[im][in], 0, 0, 0);
        acc[im][in] = __builtin_amdgcn_mfma_f32_16x16x32_bf16(
            afh[im], bfl[in], acc[im][in], 0, 0, 0);
      }
  }

#pragma unroll
  for (int im = 0; im < 4; ++im) {
    const int rbase = row0 + wr + im * 16 + kg * 4;
    float rsv[4];
#pragma unroll
    for (int r = 0; r < 4; ++r) rsv[r] = 1.0f / rsb[rbase + r];
#pragma unroll
    for (int in = 0; in < 4; ++in) {
      const int col = col0 + wc + in * 16 + fcol;
#pragma unroll
      for (int r = 0; r < 4; ++r)
        Cb[(size_t)(rbase + r) * 256 + col] = acc[im][in][r] * rsv[r];
    }
  }
}

// ---------------------------------------------------------------------------
// K4: out = X @ Wl + bl. bf16x3 (3-term) MFMA. B staged lane-stride-1.
// ---------------------------------------------------------------------------
__global__ __launch_bounds__(256) void gemm_mfma_kernel(
    const float* __restrict__ A, const float* __restrict__ B,
    const float* __restrict__ bias, float* __restrict__ C) {
  const int z = blockIdx.z;
  const float* Ab = A + (size_t)z * 65536;
  const float* Bb = B;  // shared Wl
  float* Cb = C + (size_t)z * 65536;

  const int row0 = blockIdx.y * 128;
  const int col0 = blockIdx.x * 128;

  __shared__ short Ah[128][40];
  __shared__ short Al[128][40];
  __shared__ short Bh[128][40];
  __shared__ short Bl[128][40];

  const int tid = threadIdx.x;
  const int w = tid >> 6;
  const int wr = (w >> 1) * 64;
  const int wc = (w & 1) * 64;
  const int lane = tid & 63;
  const int fcol = lane & 15;
  const int kg = lane >> 4;

  const int am = tid >> 1;
  const int ak = (tid & 1) * 16;
  const int nlane = tid & 31;
  const int kb = (tid >> 5) * 4;

  float4v acc[4][4];
#pragma unroll
  for (int i = 0; i < 4; ++i)
#pragma unroll
    for (int j = 0; j < 4; ++j) acc[i][j] = (float4v)(0.0f);

  for (int k0 = 0; k0 < 256; k0 += 32) {
    float4 av[4];
#pragma unroll
    for (int q = 0; q < 4; ++q)
      av[q] = *(const float4*)(Ab + (size_t)(row0 + am) * 256 + k0 + ak + q * 4);
    float fv[4][4];
#pragma unroll
    for (int i = 0; i < 4; ++i) {
      const int n = nlane + 32 * i;
#pragma unroll
      for (int j = 0; j < 4; ++j)
        fv[i][j] = Bb[(size_t)(k0 + kb + j) * 256 + col0 + n];
    }

    __syncthreads();

    {
      short h[16], l[16];
#pragma unroll
      for (int q = 0; q < 4; ++q) {
        split_bf16(av[q].x, h[q * 4 + 0], l[q * 4 + 0]);
        split_bf16(av[q].y, h[q * 4 + 1], l[q * 4 + 1]);
        split_bf16(av[q].z, h[q * 4 + 2], l[q * 4 + 2]);
        split_bf16(av[q].w, h[q * 4 + 3], l[q * 4 + 3]);
      }
      *(short8v*)&Ah[am][ak] = *(short8v*)&h[0];
      *(short8v*)&Ah[am][ak + 8] = *(short8v*)&h[8];
      *(short8v*)&Al[am][ak] = *(short8v*)&l[0];
      *(short8v*)&Al[am][ak + 8] = *(short8v*)&l[8];
    }
#pragma unroll
    for (int i = 0; i < 4; ++i) {
      const int n = nlane + 32 * i;
      short h[4], l[4];
#pragma unroll
      for (int j = 0; j < 4; ++j) split_bf16(fv[i][j], h[j], l[j]);
      *(short4v*)&Bh[n][kb] = *(short4v*)&h[0];
      *(short4v*)&Bl[n][kb] = *(short4v*)&l[0];
    }
    __syncthreads();

    short8v afh[4], afl[4], bfh[4], bfl[4];
#pragma unroll
    for (int im = 0; im < 4; ++im) {
      afh[im] = *(const short8v*)&Ah[wr + im * 16 + fcol][kg * 8];
      afl[im] = *(const short8v*)&Al[wr + im * 16 + fcol][kg * 8];
    }
#pragma unroll
    for (int in = 0; in < 4; ++in) {
      bfh[in] = *(const short8v*)&Bh[wc + in * 16 + fcol][kg * 8];
      bfl[in] = *(const short8v*)&Bl[wc + in * 16 + fcol][kg * 8];
    }
#pragma unroll
    for (int im = 0; im < 4; ++im)
#pragma unroll
      for (int in = 0; in < 4; ++in) {
        acc[im][in] = __builtin_amdgcn_mfma_f32_16x16x32_bf16(
            afh[im], bfh[in], acc[im][in], 0, 0, 0);
        acc[im][in] = __builtin_amdgcn_mfma_f32_16x16x32_bf16(
            afh[im], bfl[in], acc[im][in], 0, 0, 0);
        acc[im][in] = __builtin_amdgcn_mfma_f32_16x16x32_bf16(
            afl[im], bfh[in], acc[im][in], 0, 0, 0);
      }
  }

#pragma unroll
  for (int in = 0; in < 4; ++in) {
    const int col = col0 + wc + in * 16 + fcol;
    const float bvx = bias[col];
#pragma unroll
    for (int im = 0; im < 4; ++im) {
      const int rbase = row0 + wr + im * 16 + kg * 4;
#pragma unroll
      for (int r = 0; r < 4; ++r)
        Cb[(size_t)(rbase + r) * 256 + col] = acc[im][in][r] + bvx;
    }
  }
}

extern "C" void kernel_launch(void* const* d_in, const int* in_sizes, int n_in,
                              void* d_out, int out_size, void* d_ws,
                              size_t ws_size, hipStream_t stream) {
  const float* features = (const float*)d_in[0];
  const float* fm       = (const float*)d_in[1];
  const float* W1 = (const float*)d_in[2];
  const float* b1 = (const float*)d_in[3];
  const float* W2 = (const float*)d_in[4];
  const float* b2 = (const float*)d_in[5];
  const float* W3 = (const float*)d_in[6];
  const float* b3 = (const float*)d_in[7];
  const float* Wl = (const float*)d_in[8];
  const float* bl = (const float*)d_in[9];
  float* out = (float*)d_out;

  // ws layout (44.0 MB):
  //   tbl      @ 0       .. 524KB
  //   rowsumF  @ 576KB   .. 608KB   (8192 f32)
  //   counter  @ 640KB   (4B), worklist follows (512KB)
  //   adj_bin  @ 2.0MB   .. 6.2MB   (bf16 ushort)
  //   corr     @ 10.5MB  .. 18.9MB  (f32, dead after decide_fast)
  //   X        @ 10.5MB  .. 44.0MB  (f32, overwrites corr - safe)
  char* ws = (char*)d_ws;
  float* tbl          = (float*)ws;
  float* rowsumF      = (float*)(ws + 576u * 1024u);
  uint32_t* counter   = (uint32_t*)(ws + 640u * 1024u);
  uint32_t* worklist  = counter + 16;
  unsigned short* adj = (unsigned short*)(ws + 2u * 1024u * 1024u);
  float* corr         = (float*)(ws + 10800u * 1024u);
  float* X            = (float*)(ws + 10800u * 1024u);

  corr_table_kernel<<<dim3(641), 256, 0, stream>>>(fm, corr, W1, b1, W2, b2,
                                                   W3, b3, tbl, counter);
  decide_fast_kernel<<<dim3(8192), 256, 0, stream>>>(corr, tbl, adj, counter,
                                                     worklist, rowsumF);
  decide_exact_kernel<<<dim3(2048), 256, 0, stream>>>(fm, counter, worklist,
                                                      W1, b1, W2, b2, W3, b3,
                                                      adj, rowsumF);
  // X[b,c] = (1/rowsum) * (adj[b] @ F[b,c])   (X overwrites corr - consumed)
  gemm_binA_kernel<<<dim3(2, 2, 128), 256, 0, stream>>>(adj, features,
                                                        rowsumF, X);
  // out[b,c] = X[b,c] @ Wl + bl
  gemm_mfma_kernel<<<dim3(2, 2, 128), 256, 0, stream>>>(X, Wl, bl, out);
}